// Round 10
// baseline (283.196 us; speedup 1.0000x reference)
//
#include <hip/hip_runtime.h>
#include <cstdint>
#include <cstddef>

#define N_NODES 16384
#define E_EDGES 262144
#define FIN     128
#define DIM     64
#define HID     256
#define NEG     0.2f

typedef _Float16 h8 __attribute__((ext_vector_type(8)));
typedef _Float16 h4 __attribute__((ext_vector_type(4)));
typedef _Float16 h2 __attribute__((ext_vector_type(2)));
typedef float    f32x4 __attribute__((ext_vector_type(4)));
typedef float    f32x2 __attribute__((ext_vector_type(2)));

// ---------------------------------------------------------------------------
// CSR build: histogram -> scan -> scatter
// ---------------------------------------------------------------------------
__global__ __launch_bounds__(256) void hist_kernel(const int* __restrict__ dst,
                                                   int* __restrict__ cnt) {
    int i = blockIdx.x * 256 + threadIdx.x;
    if (i < E_EDGES) atomicAdd(&cnt[dst[i]], 1);
}

// Parallel scan: 256 threads x 64 counts, int4 loads, wave shfl_up scan.
__global__ __launch_bounds__(256) void csr_scan_kernel(const int* __restrict__ cnt,
                                                       int* __restrict__ offs,
                                                       int* __restrict__ cursor) {
    __shared__ int wsum[4];
    int tid = threadIdx.x, lane = tid & 63, w = tid >> 6;
    int base = tid * 64;
    const int4* c4 = (const int4*)(cnt + base);
    int4 v[16];
    int s = 0;
#pragma unroll
    for (int i = 0; i < 16; ++i) {
        v[i] = c4[i];
        s += v[i].x + v[i].y + v[i].z + v[i].w;
    }
    int scan = s;
#pragma unroll
    for (int off = 1; off < 64; off <<= 1) {
        int t = __shfl_up(scan, off);
        if (lane >= off) scan += t;
    }
    if (lane == 63) wsum[w] = scan;
    __syncthreads();
    int wbase = 0;
#pragma unroll
    for (int i = 0; i < 4; ++i) if (i < w) wbase += wsum[i];
    int run = wbase + (scan - s);          // exclusive prefix for this thread
#pragma unroll
    for (int i = 0; i < 16; ++i) {
        int4 o;
        o.x = run;
        o.y = o.x + v[i].x;
        o.z = o.y + v[i].y;
        o.w = o.z + v[i].z;
        *(int4*)(offs + base + 4 * i) = o;
        *(int4*)(cursor + base + 4 * i) = o;
        run = o.w + v[i].w;
    }
    if (tid == 255) offs[N_NODES] = run;
}

__global__ __launch_bounds__(256) void scatter_kernel(const int* __restrict__ src,
                                                      const int* __restrict__ dst,
                                                      int* __restrict__ cursor,
                                                      int* __restrict__ esrc) {
    int i = blockIdx.x * 256 + threadIdx.x;
    if (i < E_EDGES) {
        int p = atomicAdd(&cursor[dst[i]], 1);
        esrc[p] = src[i];
    }
}

// ---------------------------------------------------------------------------
// Multi-job weight pack + cnt-zero (job y==10).
// fp32 W[Ksrc][Nsrc] -> fp16 Wp[k>>3][NT][8] @ colOff.
// ---------------------------------------------------------------------------
struct PackJob { const float* W; _Float16* dst; int Ksrc, Nsrc, NT, colOff; };
struct PackJobs { PackJob j[10]; };

__global__ __launch_bounds__(256) void pack_all_kernel(PackJobs jobs, int* __restrict__ cnt) {
    int i = blockIdx.x * 256 + threadIdx.x;
    if (blockIdx.y == 10) {
        if (i < N_NODES) cnt[i] = 0;
        return;
    }
    PackJob jb = jobs.j[blockIdx.y];
    if (i < jb.Ksrc * jb.Nsrc) {
        int k = i / jb.Nsrc, n = i % jb.Nsrc;
        jb.dst[((size_t)(k >> 3) * jb.NT + jb.colOff + n) * 8 + (k & 7)] = (_Float16)jb.W[i];
    }
}

// ---------------------------------------------------------------------------
// MFMA GEMM, 64-wide output, 1 wave/block (64 rows): out = act(A@Wp + bias)
// IN32: A is fp32, converted in-register (fuses the cast).
// ---------------------------------------------------------------------------
template<int K, bool RELU, bool O16, bool IN32>
__global__ __launch_bounds__(64) void mfma_n64_kernel(const void* __restrict__ Av,
                                                      const _Float16* __restrict__ Wp,
                                                      const float* __restrict__ bias,
                                                      void* __restrict__ outv) {
    int lane = threadIdx.x;
    int rowBase = blockIdx.x * 64;
    int l15 = lane & 15, l4 = lane >> 4;

    f32x4 acc[4][4] = {};
#pragma unroll
    for (int ks = 0; ks < K / 32; ++ks) {
        h8 af[4], bf[4];
#pragma unroll
        for (int mi = 0; mi < 4; ++mi) {
            if constexpr (IN32) {
                const float* ap = (const float*)Av + (size_t)(rowBase + mi * 16 + l15) * K + ks * 32 + l4 * 8;
                float4 a0 = *(const float4*)ap;
                float4 a1 = *(const float4*)(ap + 4);
                h8 v;
                v[0] = (_Float16)a0.x; v[1] = (_Float16)a0.y;
                v[2] = (_Float16)a0.z; v[3] = (_Float16)a0.w;
                v[4] = (_Float16)a1.x; v[5] = (_Float16)a1.y;
                v[6] = (_Float16)a1.z; v[7] = (_Float16)a1.w;
                af[mi] = v;
            } else {
                af[mi] = *(const h8*)((const _Float16*)Av + (size_t)(rowBase + mi * 16 + l15) * K + ks * 32 + l4 * 8);
            }
        }
#pragma unroll
        for (int ni = 0; ni < 4; ++ni)
            bf[ni] = *(const h8*)(Wp + ((size_t)(ks * 4 + l4) * 64 + ni * 16 + l15) * 8);
#pragma unroll
        for (int mi = 0; mi < 4; ++mi)
#pragma unroll
            for (int ni = 0; ni < 4; ++ni)
                acc[mi][ni] = __builtin_amdgcn_mfma_f32_16x16x32_f16(af[mi], bf[ni], acc[mi][ni], 0, 0, 0);
    }
#pragma unroll
    for (int mi = 0; mi < 4; ++mi)
#pragma unroll
        for (int ni = 0; ni < 4; ++ni) {
            int c = ni * 16 + l15;
            float bv = bias[c];
#pragma unroll
            for (int q = 0; q < 4; ++q) {
                int r = rowBase + mi * 16 + l4 * 4 + q;
                float v = acc[mi][ni][q] + bv;
                if (RELU) v = fmaxf(v, 0.f);
                if constexpr (O16) ((_Float16*)outv)[(size_t)r * 64 + c] = (_Float16)v;
                else               ((float*)outv)[(size_t)r * 64 + c] = v;
            }
        }
}

// ---------------------------------------------------------------------------
// fp16 MFMA GEMM, no-LDS direct-fragment, wide (NT packed cols).
//   Tile 128 rows x 128 packed cols (4 waves 2x2). Col segments of 256 map to
//   o16a / o16b / o32(+bias fp32).
// ---------------------------------------------------------------------------
template<int K>
__global__ __launch_bounds__(256) void mfma_gemm_kernel(const _Float16* __restrict__ A,
                                                        const _Float16* __restrict__ Wp,
                                                        int NT,
                                                        _Float16* __restrict__ o16a,
                                                        _Float16* __restrict__ o16b,
                                                        float* __restrict__ o32,
                                                        const float* __restrict__ bias) {
    int tid = threadIdx.x;
    int lane = tid & 63, wid = tid >> 6;
    int wm = wid >> 1, wn = wid & 1;
    int rowBase = blockIdx.x * 128 + wm * 64;
    int colBase = blockIdx.y * 128 + wn * 64;
    int l15 = lane & 15, l4 = lane >> 4;

    f32x4 acc[4][4] = {};
#pragma unroll
    for (int ks = 0; ks < K / 32; ++ks) {
        h8 af[4], bf[4];
#pragma unroll
        for (int mi = 0; mi < 4; ++mi)
            af[mi] = *(const h8*)(A + (size_t)(rowBase + mi * 16 + l15) * K + ks * 32 + l4 * 8);
#pragma unroll
        for (int ni = 0; ni < 4; ++ni)
            bf[ni] = *(const h8*)(Wp + ((size_t)(ks * 4 + l4) * NT + colBase + ni * 16 + l15) * 8);
#pragma unroll
        for (int mi = 0; mi < 4; ++mi)
#pragma unroll
            for (int ni = 0; ni < 4; ++ni)
                acc[mi][ni] = __builtin_amdgcn_mfma_f32_16x16x32_f16(af[mi], bf[ni], acc[mi][ni], 0, 0, 0);
    }

    int seg = colBase >> 8;
    int cbase = colBase & 255;
    if (o32 != nullptr && seg == 2) {
#pragma unroll
        for (int mi = 0; mi < 4; ++mi)
#pragma unroll
            for (int ni = 0; ni < 4; ++ni) {
                int c = cbase + ni * 16 + l15;
                float bv = bias[c];
#pragma unroll
                for (int q = 0; q < 4; ++q) {
                    int r = rowBase + mi * 16 + l4 * 4 + q;
                    o32[(size_t)r * 256 + c] = acc[mi][ni][q] + bv;
                }
            }
    } else {
        _Float16* o = (seg == 0) ? o16a : o16b;
#pragma unroll
        for (int mi = 0; mi < 4; ++mi)
#pragma unroll
            for (int ni = 0; ni < 4; ++ni) {
                int c = cbase + ni * 16 + l15;
#pragma unroll
                for (int q = 0; q < 4; ++q) {
                    int r = rowBase + mi * 16 + l4 * 4 + q;
                    o[(size_t)r * 256 + c] = (_Float16)acc[mi][ni][q];
                }
            }
    }
}

// ---------------------------------------------------------------------------
// GATv2 edge-softmax + aggregate, 16-lanes-per-edge, 2-edge-merged updates
// (R8 sweet spot: 2 edges in flight = best VGPR/ILP tradeoff; 4-edge regressed
//  via VGPR 76 -> occupancy 22%). __launch_bounds__(256,8) pins VGPR <= 64.
//   Wave = 1 node; 4 edge slots (16-lane groups); lane owns 16 dims.
// OMODE: 0 = fp32 out only, 1 = fp32 + fp16, 2 = fp16 only.
// ---------------------------------------------------------------------------
template<int H, int OMODE>
__global__ __launch_bounds__(256, 8) void gat_agg_kernel(const _Float16* __restrict__ xl,
                                                         const _Float16* __restrict__ xr,
                                                         const float* __restrict__ att,
                                                         const float* __restrict__ bias,
                                                         const float* __restrict__ resid,
                                                         const int* __restrict__ offs,
                                                         const int* __restrict__ esrc,
                                                         float* __restrict__ out,
                                                         _Float16* __restrict__ out16) {
    int tid = threadIdx.x;
    int wid = tid >> 6;
    int lane = tid & 63;
    int node = blockIdx.x * 4 + wid;
    int g  = lane >> 4;      // edge slot 0..3
    int li = lane & 15;      // owns dims [16*li, 16*li+16)

    h2 xrv[8];
    {
        const h8* xp = (const h8*)(xr + ((size_t)node << 8) + (li << 4));
        h8 a0 = xp[0], a1 = xp[1];
#pragma unroll
        for (int i = 0; i < 4; ++i) { xrv[i][0] = a0[2 * i]; xrv[i][1] = a0[2 * i + 1]; }
#pragma unroll
        for (int i = 0; i < 4; ++i) { xrv[4 + i][0] = a1[2 * i]; xrv[4 + i][1] = a1[2 * i + 1]; }
    }
    h2 attv[8];
    {
        const float4* ap = (const float4*)(att + (li << 4));
#pragma unroll
        for (int i = 0; i < 4; ++i) {
            float4 a = ap[i];
            attv[2 * i][0] = (_Float16)a.x; attv[2 * i][1] = (_Float16)a.y;
            attv[2 * i + 1][0] = (_Float16)a.z; attv[2 * i + 1][1] = (_Float16)a.w;
        }
    }
    const h2 negc = { (_Float16)NEG, (_Float16)NEG };

    // prefetch epilogue operands early (independent of the loop)
    int dbase = (li << 4) + (g << 2);
    float4 bv = *(const float4*)(bias + dbase);
    float4 rv = *(const float4*)(resid + ((size_t)node << 8) + dbase);

    float m = -1e30f, s = 0.f;
    f32x2 acc2[8];
#pragma unroll
    for (int i = 0; i < 8; ++i) acc2[i] = (f32x2){0.f, 0.f};

    int e0 = offs[node];
    int total = offs[node + 1] - e0 + 1;      // +1 self-loop (virtual idx 0)

    auto gather = [&](int srcn, h2* hv) {
        const h8* xp = (const h8*)(xl + ((size_t)srcn << 8) + (li << 4));
        h8 a0 = xp[0], a1 = xp[1];
#pragma unroll
        for (int i = 0; i < 4; ++i) { hv[i][0] = a0[2 * i]; hv[i][1] = a0[2 * i + 1]; }
#pragma unroll
        for (int i = 0; i < 4; ++i) { hv[4 + i][0] = a1[2 * i]; hv[4 + i][1] = a1[2 * i + 1]; }
    };
    auto logit = [&](const h2* hv) -> float {
        float part = 0.f;
#pragma unroll
        for (int i = 0; i < 8; ++i) {
            h2 sum = hv[i] + xrv[i];
            h2 lr = __builtin_elementwise_max(sum, sum * negc);
            part = __builtin_amdgcn_fdot2(lr, attv[i], part, false);
        }
        part += __shfl_xor(part, 1);
        part += __shfl_xor(part, 2);
        if constexpr (H == 1) {
            part += __shfl_xor(part, 4);
            part += __shfl_xor(part, 8);
        }
        return part;
    };

    int vi = g;
    // 2-edge pipeline: edges vi and vi+4
    for (; vi + 4 < total; vi += 8) {
        int sA = (vi == 0) ? node : esrc[e0 + vi - 1];
        int sB = esrc[e0 + vi + 3];
        h2 hA[8], hB[8];
        gather(sA, hA);
        gather(sB, hB);
        float lpA = logit(hA);
        float lpB = logit(hB);
        float mn = fmaxf(m, fmaxf(lpA, lpB));
        float c  = __expf(m - mn);
        float pA = __expf(lpA - mn);
        float pB = __expf(lpB - mn);
        s = s * c + pA + pB;
#pragma unroll
        for (int i = 0; i < 8; ++i) {
            f32x2 t = acc2[i] * c;
            t[0] = fmaf(pA, (float)hA[i][0], t[0]);
            t[1] = fmaf(pA, (float)hA[i][1], t[1]);
            t[0] = fmaf(pB, (float)hB[i][0], t[0]);
            t[1] = fmaf(pB, (float)hB[i][1], t[1]);
            acc2[i] = t;
        }
        m = mn;
    }
    // tail: single edges
    for (; vi < total; vi += 4) {
        int srcn = (vi == 0) ? node : esrc[e0 + vi - 1];
        h2 hA[8];
        gather(srcn, hA);
        float lp = logit(hA);
        float mn = fmaxf(m, lp);
        float c = __expf(m - mn);
        float p = __expf(lp - mn);
        s = s * c + p;
#pragma unroll
        for (int i = 0; i < 8; ++i) {
            f32x2 t = acc2[i] * c;
            t[0] = fmaf(p, (float)hA[i][0], t[0]);
            t[1] = fmaf(p, (float)hA[i][1], t[1]);
            acc2[i] = t;
        }
        m = mn;
    }

    // flash-merge the 4 edge-slot partials across lane groups
#pragma unroll
    for (int mask = 16; mask <= 32; mask <<= 1) {
        float m2 = __shfl_xor(m, mask);
        float s2 = __shfl_xor(s, mask);
        float M = fmaxf(m, m2);
        float c1 = __expf(m - M);
        float c2 = __expf(m2 - M);
        s = s * c1 + s2 * c2;
#pragma unroll
        for (int i = 0; i < 8; ++i) {
            float ax = __shfl_xor(acc2[i][0], mask);
            float ay = __shfl_xor(acc2[i][1], mask);
            acc2[i][0] = acc2[i][0] * c1 + ax * c2;
            acc2[i][1] = acc2[i][1] * c1 + ay * c2;
        }
        m = M;
    }

    // epilogue: lane stores float4 #g of its 16 dims (compile-time select)
    float inv = 1.f / s;
    float a0, a1v, a2, a3;
    if (g == 0)      { a0 = acc2[0][0]; a1v = acc2[0][1]; a2 = acc2[1][0]; a3 = acc2[1][1]; }
    else if (g == 1) { a0 = acc2[2][0]; a1v = acc2[2][1]; a2 = acc2[3][0]; a3 = acc2[3][1]; }
    else if (g == 2) { a0 = acc2[4][0]; a1v = acc2[4][1]; a2 = acc2[5][0]; a3 = acc2[5][1]; }
    else             { a0 = acc2[6][0]; a1v = acc2[6][1]; a2 = acc2[7][0]; a3 = acc2[7][1]; }
    float o0 = fmaxf(a0 * inv + bv.x, 0.f) + rv.x;
    float o1 = fmaxf(a1v * inv + bv.y, 0.f) + rv.y;
    float o2 = fmaxf(a2 * inv + bv.z, 0.f) + rv.z;
    float o3 = fmaxf(a3 * inv + bv.w, 0.f) + rv.w;
    if constexpr (OMODE != 2) {
        float4 ov = make_float4(o0, o1, o2, o3);
        *(float4*)(out + ((size_t)node << 8) + dbase) = ov;
    }
    if constexpr (OMODE != 0) {
        h4 hv;
        hv[0] = (_Float16)o0; hv[1] = (_Float16)o1;
        hv[2] = (_Float16)o2; hv[3] = (_Float16)o3;
        *(h4*)(out16 + ((size_t)node << 8) + dbase) = hv;
    }
}

// ---------------------------------------------------------------------------
// Fused MLP head, 16-row waves (4 waves/block, 64 rows/block):
//   out[n] = relu(relu(o316[n]@Wm1+bm1)@Wm2+bm2) @ Wm3 + bm3
// ---------------------------------------------------------------------------
__global__ __launch_bounds__(256) void mlp_head_kernel(const _Float16* __restrict__ A,
                                                       const _Float16* __restrict__ Wm1p,
                                                       const float* __restrict__ bm1,
                                                       const _Float16* __restrict__ Wm2p,
                                                       const float* __restrict__ bm2,
                                                       const float* __restrict__ Wm3,
                                                       const float* __restrict__ bm3,
                                                       float* __restrict__ out) {
    __shared__ _Float16 t1s[4][16][72];
    int tid = threadIdx.x;
    int lane = tid & 63, wid = tid >> 6;
    int rowBase = blockIdx.x * 64 + wid * 16;
    int l15 = lane & 15, l4 = lane >> 4;

    f32x4 acc[4] = {};
#pragma unroll
    for (int ks = 0; ks < 8; ++ks) {
        h8 af = *(const h8*)(A + (size_t)(rowBase + l15) * 256 + ks * 32 + l4 * 8);
        h8 bf[4];
#pragma unroll
        for (int ni = 0; ni < 4; ++ni)
            bf[ni] = *(const h8*)(Wm1p + ((size_t)(ks * 4 + l4) * 64 + ni * 16 + l15) * 8);
#pragma unroll
        for (int ni = 0; ni < 4; ++ni)
            acc[ni] = __builtin_amdgcn_mfma_f32_16x16x32_f16(af, bf[ni], acc[ni], 0, 0, 0);
    }
#pragma unroll
    for (int ni = 0; ni < 4; ++ni) {
        int c = ni * 16 + l15;
        float bv = bm1[c];
#pragma unroll
        for (int q = 0; q < 4; ++q)
            t1s[wid][l4 * 4 + q][c] = (_Float16)fmaxf(acc[ni][q] + bv, 0.f);
    }

    f32x4 acc2[4] = {};
#pragma unroll
    for (int ks = 0; ks < 2; ++ks) {
        h8 af = *(const h8*)&t1s[wid][l15][ks * 32 + l4 * 8];
        h8 bf[4];
#pragma unroll
        for (int ni = 0; ni < 4; ++ni)
            bf[ni] = *(const h8*)(Wm2p + ((size_t)(ks * 4 + l4) * 64 + ni * 16 + l15) * 8);
#pragma unroll
        for (int ni = 0; ni < 4; ++ni)
            acc2[ni] = __builtin_amdgcn_mfma_f32_16x16x32_f16(af, bf[ni], acc2[ni], 0, 0, 0);
    }

    float b3 = bm3[0];
    float b2v[4], w3v[4];
#pragma unroll
    for (int ni = 0; ni < 4; ++ni) {
        b2v[ni] = bm2[ni * 16 + l15];
        w3v[ni] = Wm3[ni * 16 + l15];
    }
#pragma unroll
    for (int q = 0; q < 4; ++q) {
        float part = 0.f;
#pragma unroll
        for (int ni = 0; ni < 4; ++ni)
            part += fmaxf(acc2[ni][q] + b2v[ni], 0.f) * w3v[ni];
        part += __shfl_xor(part, 1);
        part += __shfl_xor(part, 2);
        part += __shfl_xor(part, 4);
        part += __shfl_xor(part, 8);
        if (l15 == 0)
            out[rowBase + l4 * 4 + q] = part + b3;
    }
}

// ---------------------------------------------------------------------------
extern "C" void kernel_launch(void* const* d_in, const int* in_sizes, int n_in,
                              void* d_out, int out_size, void* d_ws, size_t ws_size,
                              hipStream_t stream) {
    const float* x     = (const float*)d_in[0];
    const int*   ei    = (const int*)d_in[1];
    const float* Win   = (const float*)d_in[2];
    const float* b_in  = (const float*)d_in[3];
    const float* Wskip = (const float*)d_in[4];
    const float* bskip = (const float*)d_in[5];
    const float* Wl1   = (const float*)d_in[6];
    const float* Wr1   = (const float*)d_in[7];
    const float* att1  = (const float*)d_in[8];
    const float* b1    = (const float*)d_in[9];
    const float* Wl2   = (const float*)d_in[10];
    const float* Wr2   = (const float*)d_in[11];
    const float* att2  = (const float*)d_in[12];
    const float* b2    = (const float*)d_in[13];
    const float* Wl3   = (const float*)d_in[14];
    const float* Wr3   = (const float*)d_in[15];
    const float* att3  = (const float*)d_in[16];
    const float* b3    = (const float*)d_in[17];
    const float* Wm1   = (const float*)d_in[18];
    const float* bm1   = (const float*)d_in[19];
    const float* Wm2   = (const float*)d_in[20];
    const float* bm2   = (const float*)d_in[21];
    const float* Wm3   = (const float*)d_in[22];
    const float* bm3   = (const float*)d_in[23];

    // ---- workspace layout ----
    char* p = (char*)d_ws;
    auto alloc = [&](size_t bytes) { char* r = p; p += (bytes + 255) & ~(size_t)255; return r; };
    const size_t NN = N_NODES;
    float*    skip = (float*)alloc(NN * 256 * 4);   // also out2
    float*    out1 = (float*)alloc(NN * 256 * 4);
    _Float16* o116 = (_Float16*)alloc(NN * 256 * 2);
    _Float16* o216 = (_Float16*)alloc(NN * 256 * 2);
    _Float16* o316 = o116;                          // o116 dead by gat3
    _Float16* h16  = (_Float16*)alloc(NN * 64 * 2);
    _Float16* xl16 = (_Float16*)alloc(NN * 256 * 2);
    _Float16* xr16 = (_Float16*)alloc(NN * 256 * 2);
    _Float16* Wp1  = (_Float16*)alloc((size_t)64 * 768 * 2);
    _Float16* Wp2  = (_Float16*)alloc((size_t)256 * 512 * 2);
    _Float16* Wp3  = (_Float16*)alloc((size_t)256 * 512 * 2);
    _Float16* Winp = (_Float16*)alloc((size_t)128 * 64 * 2);
    _Float16* Wm1p = (_Float16*)alloc((size_t)256 * 64 * 2);
    _Float16* Wm2p = (_Float16*)alloc((size_t)64 * 64 * 2);
    int* cnt    = (int*)alloc(N_NODES * 4);
    int* offs   = (int*)alloc((N_NODES + 1) * 4);
    int* cursor = (int*)alloc(N_NODES * 4);
    int* esrc   = (int*)alloc(E_EDGES * 4);

    const int* src = ei;
    const int* dst = ei + E_EDGES;

    // ---- pack all weights + zero cnt (one launch) ----
    PackJobs jobs = {{
        { Wl1,   Wp1,  64,  256, 768, 0   },
        { Wr1,   Wp1,  64,  256, 768, 256 },
        { Wskip, Wp1,  64,  256, 768, 512 },
        { Wl2,   Wp2,  256, 256, 512, 0   },
        { Wr2,   Wp2,  256, 256, 512, 256 },
        { Wl3,   Wp3,  256, 256, 512, 0   },
        { Wr3,   Wp3,  256, 256, 512, 256 },
        { Win,   Winp, 128, 64,  64,  0   },
        { Wm1,   Wm1p, 256, 64,  64,  0   },
        { Wm2,   Wm2p, 64,  64,  64,  0   },
    }};
    pack_all_kernel<<<dim3(256, 11), 256, 0, stream>>>(jobs, cnt);

    // ---- CSR build ----
    hist_kernel<<<E_EDGES / 256, 256, 0, stream>>>(dst, cnt);
    csr_scan_kernel<<<1, 256, 0, stream>>>(cnt, offs, cursor);
    scatter_kernel<<<E_EDGES / 256, 256, 0, stream>>>(src, dst, cursor, esrc);

    // ---- input proj: h16 = fp16(relu(x @ Win + b_in)), cast fused ----
    mfma_n64_kernel<128, true, true, true><<<N_NODES / 64, 64, 0, stream>>>(x, Winp, b_in, h16);

    // ---- conv1: xl|xr|skip in one MFMA GEMM ----
    mfma_gemm_kernel<64><<<dim3(128, 6), 256, 0, stream>>>(h16, Wp1, 768, xl16, xr16, skip, bskip);
    gat_agg_kernel<4, 1><<<N_NODES / 4, 256, 0, stream>>>(xl16, xr16, att1, b1, skip, offs, esrc, out1, o116);

    // ---- conv2 ----
    mfma_gemm_kernel<256><<<dim3(128, 4), 256, 0, stream>>>(o116, Wp2, 512, xl16, xr16, nullptr, nullptr);
    gat_agg_kernel<1, 1><<<N_NODES / 4, 256, 0, stream>>>(xl16, xr16, att2, b2, out1, offs, esrc, skip /*out2*/, o216);

    // ---- conv3 (fp16-only output) ----
    mfma_gemm_kernel<256><<<dim3(128, 4), 256, 0, stream>>>(o216, Wp3, 512, xl16, xr16, nullptr, nullptr);
    gat_agg_kernel<1, 2><<<N_NODES / 4, 256, 0, stream>>>(xl16, xr16, att3, b3, skip /*out2*/, offs, esrc, nullptr, o316);

    // ---- fused MLP head ----
    mlp_head_kernel<<<N_NODES / 64, 256, 0, stream>>>(o316, Wm1p, bm1, Wm2p, bm2, Wm3, bm3, (float*)d_out);
}

// Round 11
// 199.641 us; speedup vs baseline: 1.4185x; 1.4185x over previous
//
#include <hip/hip_runtime.h>
#include <cstdint>
#include <cstddef>

#define N_NODES 16384
#define E_EDGES 262144
#define FIN     128
#define DIM     64
#define HID     256
#define NEG     0.2f

typedef _Float16 h8 __attribute__((ext_vector_type(8)));
typedef _Float16 h4 __attribute__((ext_vector_type(4)));
typedef _Float16 h2 __attribute__((ext_vector_type(2)));
typedef float    f32x4 __attribute__((ext_vector_type(4)));
typedef float    f32x2 __attribute__((ext_vector_type(2)));

// ---------------------------------------------------------------------------
// CSR build: histogram -> scan -> scatter
// ---------------------------------------------------------------------------
__global__ __launch_bounds__(256) void hist_kernel(const int* __restrict__ dst,
                                                   int* __restrict__ cnt) {
    int i = blockIdx.x * 256 + threadIdx.x;
    if (i < E_EDGES) atomicAdd(&cnt[dst[i]], 1);
}

// Parallel scan: 256 threads x 64 counts, int4 loads, wave shfl_up scan.
__global__ __launch_bounds__(256) void csr_scan_kernel(const int* __restrict__ cnt,
                                                       int* __restrict__ offs,
                                                       int* __restrict__ cursor) {
    __shared__ int wsum[4];
    int tid = threadIdx.x, lane = tid & 63, w = tid >> 6;
    int base = tid * 64;
    const int4* c4 = (const int4*)(cnt + base);
    int4 v[16];
    int s = 0;
#pragma unroll
    for (int i = 0; i < 16; ++i) {
        v[i] = c4[i];
        s += v[i].x + v[i].y + v[i].z + v[i].w;
    }
    int scan = s;
#pragma unroll
    for (int off = 1; off < 64; off <<= 1) {
        int t = __shfl_up(scan, off);
        if (lane >= off) scan += t;
    }
    if (lane == 63) wsum[w] = scan;
    __syncthreads();
    int wbase = 0;
#pragma unroll
    for (int i = 0; i < 4; ++i) if (i < w) wbase += wsum[i];
    int run = wbase + (scan - s);          // exclusive prefix for this thread
#pragma unroll
    for (int i = 0; i < 16; ++i) {
        int4 o;
        o.x = run;
        o.y = o.x + v[i].x;
        o.z = o.y + v[i].y;
        o.w = o.z + v[i].z;
        *(int4*)(offs + base + 4 * i) = o;
        *(int4*)(cursor + base + 4 * i) = o;
        run = o.w + v[i].w;
    }
    if (tid == 255) offs[N_NODES] = run;
}

__global__ __launch_bounds__(256) void scatter_kernel(const int* __restrict__ src,
                                                      const int* __restrict__ dst,
                                                      int* __restrict__ cursor,
                                                      int* __restrict__ esrc) {
    int i = blockIdx.x * 256 + threadIdx.x;
    if (i < E_EDGES) {
        int p = atomicAdd(&cursor[dst[i]], 1);
        esrc[p] = src[i];
    }
}

// ---------------------------------------------------------------------------
// Multi-job weight pack + cnt-zero (job y==10).
// fp32 W[Ksrc][Nsrc] -> fp16 Wp[k>>3][NT][8] @ colOff.
// ---------------------------------------------------------------------------
struct PackJob { const float* W; _Float16* dst; int Ksrc, Nsrc, NT, colOff; };
struct PackJobs { PackJob j[10]; };

__global__ __launch_bounds__(256) void pack_all_kernel(PackJobs jobs, int* __restrict__ cnt) {
    int i = blockIdx.x * 256 + threadIdx.x;
    if (blockIdx.y == 10) {
        if (i < N_NODES) cnt[i] = 0;
        return;
    }
    PackJob jb = jobs.j[blockIdx.y];
    if (i < jb.Ksrc * jb.Nsrc) {
        int k = i / jb.Nsrc, n = i % jb.Nsrc;
        jb.dst[((size_t)(k >> 3) * jb.NT + jb.colOff + n) * 8 + (k & 7)] = (_Float16)jb.W[i];
    }
}

// ---------------------------------------------------------------------------
// MFMA GEMM, 64-wide output, 1 wave/block (64 rows): out = act(A@Wp + bias)
// IN32: A is fp32, converted in-register (fuses the cast).
// ---------------------------------------------------------------------------
template<int K, bool RELU, bool O16, bool IN32>
__global__ __launch_bounds__(64) void mfma_n64_kernel(const void* __restrict__ Av,
                                                      const _Float16* __restrict__ Wp,
                                                      const float* __restrict__ bias,
                                                      void* __restrict__ outv) {
    int lane = threadIdx.x;
    int rowBase = blockIdx.x * 64;
    int l15 = lane & 15, l4 = lane >> 4;

    f32x4 acc[4][4] = {};
#pragma unroll
    for (int ks = 0; ks < K / 32; ++ks) {
        h8 af[4], bf[4];
#pragma unroll
        for (int mi = 0; mi < 4; ++mi) {
            if constexpr (IN32) {
                const float* ap = (const float*)Av + (size_t)(rowBase + mi * 16 + l15) * K + ks * 32 + l4 * 8;
                float4 a0 = *(const float4*)ap;
                float4 a1 = *(const float4*)(ap + 4);
                h8 v;
                v[0] = (_Float16)a0.x; v[1] = (_Float16)a0.y;
                v[2] = (_Float16)a0.z; v[3] = (_Float16)a0.w;
                v[4] = (_Float16)a1.x; v[5] = (_Float16)a1.y;
                v[6] = (_Float16)a1.z; v[7] = (_Float16)a1.w;
                af[mi] = v;
            } else {
                af[mi] = *(const h8*)((const _Float16*)Av + (size_t)(rowBase + mi * 16 + l15) * K + ks * 32 + l4 * 8);
            }
        }
#pragma unroll
        for (int ni = 0; ni < 4; ++ni)
            bf[ni] = *(const h8*)(Wp + ((size_t)(ks * 4 + l4) * 64 + ni * 16 + l15) * 8);
#pragma unroll
        for (int mi = 0; mi < 4; ++mi)
#pragma unroll
            for (int ni = 0; ni < 4; ++ni)
                acc[mi][ni] = __builtin_amdgcn_mfma_f32_16x16x32_f16(af[mi], bf[ni], acc[mi][ni], 0, 0, 0);
    }
#pragma unroll
    for (int mi = 0; mi < 4; ++mi)
#pragma unroll
        for (int ni = 0; ni < 4; ++ni) {
            int c = ni * 16 + l15;
            float bv = bias[c];
#pragma unroll
            for (int q = 0; q < 4; ++q) {
                int r = rowBase + mi * 16 + l4 * 4 + q;
                float v = acc[mi][ni][q] + bv;
                if (RELU) v = fmaxf(v, 0.f);
                if constexpr (O16) ((_Float16*)outv)[(size_t)r * 64 + c] = (_Float16)v;
                else               ((float*)outv)[(size_t)r * 64 + c] = v;
            }
        }
}

// ---------------------------------------------------------------------------
// fp16 MFMA GEMM, no-LDS direct-fragment, wide (NT packed cols).
//   Tile 128 rows x 128 packed cols (4 waves 2x2). Col segments of 256 map to
//   o16a / o16b / o32(+bias fp32).
// ---------------------------------------------------------------------------
template<int K>
__global__ __launch_bounds__(256) void mfma_gemm_kernel(const _Float16* __restrict__ A,
                                                        const _Float16* __restrict__ Wp,
                                                        int NT,
                                                        _Float16* __restrict__ o16a,
                                                        _Float16* __restrict__ o16b,
                                                        float* __restrict__ o32,
                                                        const float* __restrict__ bias) {
    int tid = threadIdx.x;
    int lane = tid & 63, wid = tid >> 6;
    int wm = wid >> 1, wn = wid & 1;
    int rowBase = blockIdx.x * 128 + wm * 64;
    int colBase = blockIdx.y * 128 + wn * 64;
    int l15 = lane & 15, l4 = lane >> 4;

    f32x4 acc[4][4] = {};
#pragma unroll
    for (int ks = 0; ks < K / 32; ++ks) {
        h8 af[4], bf[4];
#pragma unroll
        for (int mi = 0; mi < 4; ++mi)
            af[mi] = *(const h8*)(A + (size_t)(rowBase + mi * 16 + l15) * K + ks * 32 + l4 * 8);
#pragma unroll
        for (int ni = 0; ni < 4; ++ni)
            bf[ni] = *(const h8*)(Wp + ((size_t)(ks * 4 + l4) * NT + colBase + ni * 16 + l15) * 8);
#pragma unroll
        for (int mi = 0; mi < 4; ++mi)
#pragma unroll
            for (int ni = 0; ni < 4; ++ni)
                acc[mi][ni] = __builtin_amdgcn_mfma_f32_16x16x32_f16(af[mi], bf[ni], acc[mi][ni], 0, 0, 0);
    }

    int seg = colBase >> 8;
    int cbase = colBase & 255;
    if (o32 != nullptr && seg == 2) {
#pragma unroll
        for (int mi = 0; mi < 4; ++mi)
#pragma unroll
            for (int ni = 0; ni < 4; ++ni) {
                int c = cbase + ni * 16 + l15;
                float bv = bias[c];
#pragma unroll
                for (int q = 0; q < 4; ++q) {
                    int r = rowBase + mi * 16 + l4 * 4 + q;
                    o32[(size_t)r * 256 + c] = acc[mi][ni][q] + bv;
                }
            }
    } else {
        _Float16* o = (seg == 0) ? o16a : o16b;
#pragma unroll
        for (int mi = 0; mi < 4; ++mi)
#pragma unroll
            for (int ni = 0; ni < 4; ++ni) {
                int c = cbase + ni * 16 + l15;
#pragma unroll
                for (int q = 0; q < 4; ++q) {
                    int r = rowBase + mi * 16 + l4 * 4 + q;
                    o[(size_t)r * 256 + c] = (_Float16)acc[mi][ni][q];
                }
            }
    }
}

// ---------------------------------------------------------------------------
// GATv2 edge-softmax + aggregate, 16-lanes-per-edge, 2-edge-merged updates.
// NOTE: no min-waves __launch_bounds__ clamp — R10 showed (256,8) forces
// VGPR 52->32 with scratch spills (FETCH 61->172MB, 3x slower). The natural
// 52-VGPR / ~5 waves/SIMD point is the measured optimum (R8: 199us total).
//   Wave = 1 node; 4 edge slots (16-lane groups); lane owns 16 dims.
// OMODE: 0 = fp32 out only, 1 = fp32 + fp16, 2 = fp16 only.
// ---------------------------------------------------------------------------
template<int H, int OMODE>
__global__ __launch_bounds__(256) void gat_agg_kernel(const _Float16* __restrict__ xl,
                                                      const _Float16* __restrict__ xr,
                                                      const float* __restrict__ att,
                                                      const float* __restrict__ bias,
                                                      const float* __restrict__ resid,
                                                      const int* __restrict__ offs,
                                                      const int* __restrict__ esrc,
                                                      float* __restrict__ out,
                                                      _Float16* __restrict__ out16) {
    int tid = threadIdx.x;
    int wid = tid >> 6;
    int lane = tid & 63;
    int node = blockIdx.x * 4 + wid;
    int g  = lane >> 4;      // edge slot 0..3
    int li = lane & 15;      // owns dims [16*li, 16*li+16)

    h2 xrv[8];
    {
        const h8* xp = (const h8*)(xr + ((size_t)node << 8) + (li << 4));
        h8 a0 = xp[0], a1 = xp[1];
#pragma unroll
        for (int i = 0; i < 4; ++i) { xrv[i][0] = a0[2 * i]; xrv[i][1] = a0[2 * i + 1]; }
#pragma unroll
        for (int i = 0; i < 4; ++i) { xrv[4 + i][0] = a1[2 * i]; xrv[4 + i][1] = a1[2 * i + 1]; }
    }
    h2 attv[8];
    {
        const float4* ap = (const float4*)(att + (li << 4));
#pragma unroll
        for (int i = 0; i < 4; ++i) {
            float4 a = ap[i];
            attv[2 * i][0] = (_Float16)a.x; attv[2 * i][1] = (_Float16)a.y;
            attv[2 * i + 1][0] = (_Float16)a.z; attv[2 * i + 1][1] = (_Float16)a.w;
        }
    }
    const h2 negc = { (_Float16)NEG, (_Float16)NEG };

    // prefetch epilogue operands early (independent of the loop)
    int dbase = (li << 4) + (g << 2);
    float4 bv = *(const float4*)(bias + dbase);
    float4 rv = *(const float4*)(resid + ((size_t)node << 8) + dbase);

    float m = -1e30f, s = 0.f;
    f32x2 acc2[8];
#pragma unroll
    for (int i = 0; i < 8; ++i) acc2[i] = (f32x2){0.f, 0.f};

    int e0 = offs[node];
    int total = offs[node + 1] - e0 + 1;      // +1 self-loop (virtual idx 0)

    auto gather = [&](int srcn, h2* hv) {
        const h8* xp = (const h8*)(xl + ((size_t)srcn << 8) + (li << 4));
        h8 a0 = xp[0], a1 = xp[1];
#pragma unroll
        for (int i = 0; i < 4; ++i) { hv[i][0] = a0[2 * i]; hv[i][1] = a0[2 * i + 1]; }
#pragma unroll
        for (int i = 0; i < 4; ++i) { hv[4 + i][0] = a1[2 * i]; hv[4 + i][1] = a1[2 * i + 1]; }
    };
    auto logit = [&](const h2* hv) -> float {
        float part = 0.f;
#pragma unroll
        for (int i = 0; i < 8; ++i) {
            h2 sum = hv[i] + xrv[i];
            h2 lr = __builtin_elementwise_max(sum, sum * negc);
            part = __builtin_amdgcn_fdot2(lr, attv[i], part, false);
        }
        part += __shfl_xor(part, 1);
        part += __shfl_xor(part, 2);
        if constexpr (H == 1) {
            part += __shfl_xor(part, 4);
            part += __shfl_xor(part, 8);
        }
        return part;
    };

    int vi = g;
    // 2-edge pipeline: edges vi and vi+4
    for (; vi + 4 < total; vi += 8) {
        int sA = (vi == 0) ? node : esrc[e0 + vi - 1];
        int sB = esrc[e0 + vi + 3];
        h2 hA[8], hB[8];
        gather(sA, hA);
        gather(sB, hB);
        float lpA = logit(hA);
        float lpB = logit(hB);
        float mn = fmaxf(m, fmaxf(lpA, lpB));
        float c  = __expf(m - mn);
        float pA = __expf(lpA - mn);
        float pB = __expf(lpB - mn);
        s = s * c + pA + pB;
#pragma unroll
        for (int i = 0; i < 8; ++i) {
            f32x2 t = acc2[i] * c;
            t[0] = fmaf(pA, (float)hA[i][0], t[0]);
            t[1] = fmaf(pA, (float)hA[i][1], t[1]);
            t[0] = fmaf(pB, (float)hB[i][0], t[0]);
            t[1] = fmaf(pB, (float)hB[i][1], t[1]);
            acc2[i] = t;
        }
        m = mn;
    }
    // tail: single edges
    for (; vi < total; vi += 4) {
        int srcn = (vi == 0) ? node : esrc[e0 + vi - 1];
        h2 hA[8];
        gather(srcn, hA);
        float lp = logit(hA);
        float mn = fmaxf(m, lp);
        float c = __expf(m - mn);
        float p = __expf(lp - mn);
        s = s * c + p;
#pragma unroll
        for (int i = 0; i < 8; ++i) {
            f32x2 t = acc2[i] * c;
            t[0] = fmaf(p, (float)hA[i][0], t[0]);
            t[1] = fmaf(p, (float)hA[i][1], t[1]);
            acc2[i] = t;
        }
        m = mn;
    }

    // flash-merge the 4 edge-slot partials across lane groups
#pragma unroll
    for (int mask = 16; mask <= 32; mask <<= 1) {
        float m2 = __shfl_xor(m, mask);
        float s2 = __shfl_xor(s, mask);
        float M = fmaxf(m, m2);
        float c1 = __expf(m - M);
        float c2 = __expf(m2 - M);
        s = s * c1 + s2 * c2;
#pragma unroll
        for (int i = 0; i < 8; ++i) {
            float ax = __shfl_xor(acc2[i][0], mask);
            float ay = __shfl_xor(acc2[i][1], mask);
            acc2[i][0] = acc2[i][0] * c1 + ax * c2;
            acc2[i][1] = acc2[i][1] * c1 + ay * c2;
        }
        m = M;
    }

    // epilogue: lane stores float4 #g of its 16 dims (compile-time select)
    float inv = 1.f / s;
    float a0, a1v, a2, a3;
    if (g == 0)      { a0 = acc2[0][0]; a1v = acc2[0][1]; a2 = acc2[1][0]; a3 = acc2[1][1]; }
    else if (g == 1) { a0 = acc2[2][0]; a1v = acc2[2][1]; a2 = acc2[3][0]; a3 = acc2[3][1]; }
    else if (g == 2) { a0 = acc2[4][0]; a1v = acc2[4][1]; a2 = acc2[5][0]; a3 = acc2[5][1]; }
    else             { a0 = acc2[6][0]; a1v = acc2[6][1]; a2 = acc2[7][0]; a3 = acc2[7][1]; }
    float o0 = fmaxf(a0 * inv + bv.x, 0.f) + rv.x;
    float o1 = fmaxf(a1v * inv + bv.y, 0.f) + rv.y;
    float o2 = fmaxf(a2 * inv + bv.z, 0.f) + rv.z;
    float o3 = fmaxf(a3 * inv + bv.w, 0.f) + rv.w;
    if constexpr (OMODE != 2) {
        float4 ov = make_float4(o0, o1, o2, o3);
        *(float4*)(out + ((size_t)node << 8) + dbase) = ov;
    }
    if constexpr (OMODE != 0) {
        h4 hv;
        hv[0] = (_Float16)o0; hv[1] = (_Float16)o1;
        hv[2] = (_Float16)o2; hv[3] = (_Float16)o3;
        *(h4*)(out16 + ((size_t)node << 8) + dbase) = hv;
    }
}

// ---------------------------------------------------------------------------
// Fused MLP head, 16-row waves (4 waves/block, 64 rows/block):
//   out[n] = relu(relu(o316[n]@Wm1+bm1)@Wm2+bm2) @ Wm3 + bm3
// ---------------------------------------------------------------------------
__global__ __launch_bounds__(256) void mlp_head_kernel(const _Float16* __restrict__ A,
                                                       const _Float16* __restrict__ Wm1p,
                                                       const float* __restrict__ bm1,
                                                       const _Float16* __restrict__ Wm2p,
                                                       const float* __restrict__ bm2,
                                                       const float* __restrict__ Wm3,
                                                       const float* __restrict__ bm3,
                                                       float* __restrict__ out) {
    __shared__ _Float16 t1s[4][16][72];
    int tid = threadIdx.x;
    int lane = tid & 63, wid = tid >> 6;
    int rowBase = blockIdx.x * 64 + wid * 16;
    int l15 = lane & 15, l4 = lane >> 4;

    f32x4 acc[4] = {};
#pragma unroll
    for (int ks = 0; ks < 8; ++ks) {
        h8 af = *(const h8*)(A + (size_t)(rowBase + l15) * 256 + ks * 32 + l4 * 8);
        h8 bf[4];
#pragma unroll
        for (int ni = 0; ni < 4; ++ni)
            bf[ni] = *(const h8*)(Wm1p + ((size_t)(ks * 4 + l4) * 64 + ni * 16 + l15) * 8);
#pragma unroll
        for (int ni = 0; ni < 4; ++ni)
            acc[ni] = __builtin_amdgcn_mfma_f32_16x16x32_f16(af, bf[ni], acc[ni], 0, 0, 0);
    }
#pragma unroll
    for (int ni = 0; ni < 4; ++ni) {
        int c = ni * 16 + l15;
        float bv = bm1[c];
#pragma unroll
        for (int q = 0; q < 4; ++q)
            t1s[wid][l4 * 4 + q][c] = (_Float16)fmaxf(acc[ni][q] + bv, 0.f);
    }

    f32x4 acc2[4] = {};
#pragma unroll
    for (int ks = 0; ks < 2; ++ks) {
        h8 af = *(const h8*)&t1s[wid][l15][ks * 32 + l4 * 8];
        h8 bf[4];
#pragma unroll
        for (int ni = 0; ni < 4; ++ni)
            bf[ni] = *(const h8*)(Wm2p + ((size_t)(ks * 4 + l4) * 64 + ni * 16 + l15) * 8);
#pragma unroll
        for (int ni = 0; ni < 4; ++ni)
            acc2[ni] = __builtin_amdgcn_mfma_f32_16x16x32_f16(af, bf[ni], acc2[ni], 0, 0, 0);
    }

    float b3 = bm3[0];
    float b2v[4], w3v[4];
#pragma unroll
    for (int ni = 0; ni < 4; ++ni) {
        b2v[ni] = bm2[ni * 16 + l15];
        w3v[ni] = Wm3[ni * 16 + l15];
    }
#pragma unroll
    for (int q = 0; q < 4; ++q) {
        float part = 0.f;
#pragma unroll
        for (int ni = 0; ni < 4; ++ni)
            part += fmaxf(acc2[ni][q] + b2v[ni], 0.f) * w3v[ni];
        part += __shfl_xor(part, 1);
        part += __shfl_xor(part, 2);
        part += __shfl_xor(part, 4);
        part += __shfl_xor(part, 8);
        if (l15 == 0)
            out[rowBase + l4 * 4 + q] = part + b3;
    }
}

// ---------------------------------------------------------------------------
extern "C" void kernel_launch(void* const* d_in, const int* in_sizes, int n_in,
                              void* d_out, int out_size, void* d_ws, size_t ws_size,
                              hipStream_t stream) {
    const float* x     = (const float*)d_in[0];
    const int*   ei    = (const int*)d_in[1];
    const float* Win   = (const float*)d_in[2];
    const float* b_in  = (const float*)d_in[3];
    const float* Wskip = (const float*)d_in[4];
    const float* bskip = (const float*)d_in[5];
    const float* Wl1   = (const float*)d_in[6];
    const float* Wr1   = (const float*)d_in[7];
    const float* att1  = (const float*)d_in[8];
    const float* b1    = (const float*)d_in[9];
    const float* Wl2   = (const float*)d_in[10];
    const float* Wr2   = (const float*)d_in[11];
    const float* att2  = (const float*)d_in[12];
    const float* b2    = (const float*)d_in[13];
    const float* Wl3   = (const float*)d_in[14];
    const float* Wr3   = (const float*)d_in[15];
    const float* att3  = (const float*)d_in[16];
    const float* b3    = (const float*)d_in[17];
    const float* Wm1   = (const float*)d_in[18];
    const float* bm1   = (const float*)d_in[19];
    const float* Wm2   = (const float*)d_in[20];
    const float* bm2   = (const float*)d_in[21];
    const float* Wm3   = (const float*)d_in[22];
    const float* bm3   = (const float*)d_in[23];

    // ---- workspace layout ----
    char* p = (char*)d_ws;
    auto alloc = [&](size_t bytes) { char* r = p; p += (bytes + 255) & ~(size_t)255; return r; };
    const size_t NN = N_NODES;
    float*    skip = (float*)alloc(NN * 256 * 4);   // also out2
    float*    out1 = (float*)alloc(NN * 256 * 4);
    _Float16* o116 = (_Float16*)alloc(NN * 256 * 2);
    _Float16* o216 = (_Float16*)alloc(NN * 256 * 2);
    _Float16* o316 = o116;                          // o116 dead by gat3
    _Float16* h16  = (_Float16*)alloc(NN * 64 * 2);
    _Float16* xl16 = (_Float16*)alloc(NN * 256 * 2);
    _Float16* xr16 = (_Float16*)alloc(NN * 256 * 2);
    _Float16* Wp1  = (_Float16*)alloc((size_t)64 * 768 * 2);
    _Float16* Wp2  = (_Float16*)alloc((size_t)256 * 512 * 2);
    _Float16* Wp3  = (_Float16*)alloc((size_t)256 * 512 * 2);
    _Float16* Winp = (_Float16*)alloc((size_t)128 * 64 * 2);
    _Float16* Wm1p = (_Float16*)alloc((size_t)256 * 64 * 2);
    _Float16* Wm2p = (_Float16*)alloc((size_t)64 * 64 * 2);
    int* cnt    = (int*)alloc(N_NODES * 4);
    int* offs   = (int*)alloc((N_NODES + 1) * 4);
    int* cursor = (int*)alloc(N_NODES * 4);
    int* esrc   = (int*)alloc(E_EDGES * 4);

    const int* src = ei;
    const int* dst = ei + E_EDGES;

    // ---- pack all weights + zero cnt (one launch) ----
    PackJobs jobs = {{
        { Wl1,   Wp1,  64,  256, 768, 0   },
        { Wr1,   Wp1,  64,  256, 768, 256 },
        { Wskip, Wp1,  64,  256, 768, 512 },
        { Wl2,   Wp2,  256, 256, 512, 0   },
        { Wr2,   Wp2,  256, 256, 512, 256 },
        { Wl3,   Wp3,  256, 256, 512, 0   },
        { Wr3,   Wp3,  256, 256, 512, 256 },
        { Win,   Winp, 128, 64,  64,  0   },
        { Wm1,   Wm1p, 256, 64,  64,  0   },
        { Wm2,   Wm2p, 64,  64,  64,  0   },
    }};
    pack_all_kernel<<<dim3(256, 11), 256, 0, stream>>>(jobs, cnt);

    // ---- CSR build ----
    hist_kernel<<<E_EDGES / 256, 256, 0, stream>>>(dst, cnt);
    csr_scan_kernel<<<1, 256, 0, stream>>>(cnt, offs, cursor);
    scatter_kernel<<<E_EDGES / 256, 256, 0, stream>>>(src, dst, cursor, esrc);

    // ---- input proj: h16 = fp16(relu(x @ Win + b_in)), cast fused ----
    mfma_n64_kernel<128, true, true, true><<<N_NODES / 64, 64, 0, stream>>>(x, Winp, b_in, h16);

    // ---- conv1: xl|xr|skip in one MFMA GEMM ----
    mfma_gemm_kernel<64><<<dim3(128, 6), 256, 0, stream>>>(h16, Wp1, 768, xl16, xr16, skip, bskip);
    gat_agg_kernel<4, 1><<<N_NODES / 4, 256, 0, stream>>>(xl16, xr16, att1, b1, skip, offs, esrc, out1, o116);

    // ---- conv2 ----
    mfma_gemm_kernel<256><<<dim3(128, 4), 256, 0, stream>>>(o116, Wp2, 512, xl16, xr16, nullptr, nullptr);
    gat_agg_kernel<1, 1><<<N_NODES / 4, 256, 0, stream>>>(xl16, xr16, att2, b2, out1, offs, esrc, skip /*out2*/, o216);

    // ---- conv3 (fp16-only output) ----
    mfma_gemm_kernel<256><<<dim3(128, 4), 256, 0, stream>>>(o216, Wp3, 512, xl16, xr16, nullptr, nullptr);
    gat_agg_kernel<1, 2><<<N_NODES / 4, 256, 0, stream>>>(xl16, xr16, att3, b3, skip /*out2*/, offs, esrc, nullptr, o316);

    // ---- fused MLP head ----
    mlp_head_kernel<<<N_NODES / 64, 256, 0, stream>>>(o316, Wm1p, bm1, Wm2p, bm2, Wm3, bm3, (float*)d_out);
}

// Round 12
// 195.327 us; speedup vs baseline: 1.4499x; 1.0221x over previous
//
#include <hip/hip_runtime.h>
#include <cstdint>
#include <cstddef>

#define N_NODES 16384
#define E_EDGES 262144
#define FIN     128
#define DIM     64
#define HID     256
#define NEG     0.2f

typedef _Float16 h8 __attribute__((ext_vector_type(8)));
typedef _Float16 h4 __attribute__((ext_vector_type(4)));
typedef _Float16 h2 __attribute__((ext_vector_type(2)));
typedef float    f32x4 __attribute__((ext_vector_type(4)));
typedef float    f32x2 __attribute__((ext_vector_type(2)));

// ---------------------------------------------------------------------------
// CSR build: histogram -> scan -> scatter
// ---------------------------------------------------------------------------
__global__ __launch_bounds__(256) void hist_kernel(const int* __restrict__ dst,
                                                   int* __restrict__ cnt) {
    int i = blockIdx.x * 256 + threadIdx.x;
    if (i < E_EDGES) atomicAdd(&cnt[dst[i]], 1);
}

// Parallel scan: 256 threads x 64 counts, int4 loads, wave shfl_up scan.
__global__ __launch_bounds__(256) void csr_scan_kernel(const int* __restrict__ cnt,
                                                       int* __restrict__ offs,
                                                       int* __restrict__ cursor) {
    __shared__ int wsum[4];
    int tid = threadIdx.x, lane = tid & 63, w = tid >> 6;
    int base = tid * 64;
    const int4* c4 = (const int4*)(cnt + base);
    int4 v[16];
    int s = 0;
#pragma unroll
    for (int i = 0; i < 16; ++i) {
        v[i] = c4[i];
        s += v[i].x + v[i].y + v[i].z + v[i].w;
    }
    int scan = s;
#pragma unroll
    for (int off = 1; off < 64; off <<= 1) {
        int t = __shfl_up(scan, off);
        if (lane >= off) scan += t;
    }
    if (lane == 63) wsum[w] = scan;
    __syncthreads();
    int wbase = 0;
#pragma unroll
    for (int i = 0; i < 4; ++i) if (i < w) wbase += wsum[i];
    int run = wbase + (scan - s);          // exclusive prefix for this thread
#pragma unroll
    for (int i = 0; i < 16; ++i) {
        int4 o;
        o.x = run;
        o.y = o.x + v[i].x;
        o.z = o.y + v[i].y;
        o.w = o.z + v[i].z;
        *(int4*)(offs + base + 4 * i) = o;
        *(int4*)(cursor + base + 4 * i) = o;
        run = o.w + v[i].w;
    }
    if (tid == 255) offs[N_NODES] = run;
}

__global__ __launch_bounds__(256) void scatter_kernel(const int* __restrict__ src,
                                                      const int* __restrict__ dst,
                                                      int* __restrict__ cursor,
                                                      int* __restrict__ esrc) {
    int i = blockIdx.x * 256 + threadIdx.x;
    if (i < E_EDGES) {
        int p = atomicAdd(&cursor[dst[i]], 1);
        esrc[p] = src[i];
    }
}

// ---------------------------------------------------------------------------
// Multi-job weight pack + cnt-zero (job y==10).
// fp32 W[Ksrc][Nsrc] -> fp16 Wp[k>>3][NT][8] @ colOff.
// ---------------------------------------------------------------------------
struct PackJob { const float* W; _Float16* dst; int Ksrc, Nsrc, NT, colOff; };
struct PackJobs { PackJob j[10]; };

__global__ __launch_bounds__(256) void pack_all_kernel(PackJobs jobs, int* __restrict__ cnt) {
    int i = blockIdx.x * 256 + threadIdx.x;
    if (blockIdx.y == 10) {
        if (i < N_NODES) cnt[i] = 0;
        return;
    }
    PackJob jb = jobs.j[blockIdx.y];
    if (i < jb.Ksrc * jb.Nsrc) {
        int k = i / jb.Nsrc, n = i % jb.Nsrc;
        jb.dst[((size_t)(k >> 3) * jb.NT + jb.colOff + n) * 8 + (k & 7)] = (_Float16)jb.W[i];
    }
}

// ---------------------------------------------------------------------------
// MFMA GEMM, 64-wide output, 1 wave/block (64 rows): out = act(A@Wp + bias)
// IN32: A is fp32, converted in-register (fuses the cast).
// ---------------------------------------------------------------------------
template<int K, bool RELU, bool O16, bool IN32>
__global__ __launch_bounds__(64) void mfma_n64_kernel(const void* __restrict__ Av,
                                                      const _Float16* __restrict__ Wp,
                                                      const float* __restrict__ bias,
                                                      void* __restrict__ outv) {
    int lane = threadIdx.x;
    int rowBase = blockIdx.x * 64;
    int l15 = lane & 15, l4 = lane >> 4;

    f32x4 acc[4][4] = {};
#pragma unroll
    for (int ks = 0; ks < K / 32; ++ks) {
        h8 af[4], bf[4];
#pragma unroll
        for (int mi = 0; mi < 4; ++mi) {
            if constexpr (IN32) {
                const float* ap = (const float*)Av + (size_t)(rowBase + mi * 16 + l15) * K + ks * 32 + l4 * 8;
                float4 a0 = *(const float4*)ap;
                float4 a1 = *(const float4*)(ap + 4);
                h8 v;
                v[0] = (_Float16)a0.x; v[1] = (_Float16)a0.y;
                v[2] = (_Float16)a0.z; v[3] = (_Float16)a0.w;
                v[4] = (_Float16)a1.x; v[5] = (_Float16)a1.y;
                v[6] = (_Float16)a1.z; v[7] = (_Float16)a1.w;
                af[mi] = v;
            } else {
                af[mi] = *(const h8*)((const _Float16*)Av + (size_t)(rowBase + mi * 16 + l15) * K + ks * 32 + l4 * 8);
            }
        }
#pragma unroll
        for (int ni = 0; ni < 4; ++ni)
            bf[ni] = *(const h8*)(Wp + ((size_t)(ks * 4 + l4) * 64 + ni * 16 + l15) * 8);
#pragma unroll
        for (int mi = 0; mi < 4; ++mi)
#pragma unroll
            for (int ni = 0; ni < 4; ++ni)
                acc[mi][ni] = __builtin_amdgcn_mfma_f32_16x16x32_f16(af[mi], bf[ni], acc[mi][ni], 0, 0, 0);
    }
#pragma unroll
    for (int mi = 0; mi < 4; ++mi)
#pragma unroll
        for (int ni = 0; ni < 4; ++ni) {
            int c = ni * 16 + l15;
            float bv = bias[c];
#pragma unroll
            for (int q = 0; q < 4; ++q) {
                int r = rowBase + mi * 16 + l4 * 4 + q;
                float v = acc[mi][ni][q] + bv;
                if (RELU) v = fmaxf(v, 0.f);
                if constexpr (O16) ((_Float16*)outv)[(size_t)r * 64 + c] = (_Float16)v;
                else               ((float*)outv)[(size_t)r * 64 + c] = v;
            }
        }
}

// ---------------------------------------------------------------------------
// fp16 MFMA GEMM, no-LDS direct-fragment, wide (NT packed cols).
//   Tile 128 rows x 128 packed cols (4 waves 2x2). Col segments of 256 map to
//   o16a / o16b / o32(+bias fp32).
// ---------------------------------------------------------------------------
template<int K>
__global__ __launch_bounds__(256) void mfma_gemm_kernel(const _Float16* __restrict__ A,
                                                        const _Float16* __restrict__ Wp,
                                                        int NT,
                                                        _Float16* __restrict__ o16a,
                                                        _Float16* __restrict__ o16b,
                                                        float* __restrict__ o32,
                                                        const float* __restrict__ bias) {
    int tid = threadIdx.x;
    int lane = tid & 63, wid = tid >> 6;
    int wm = wid >> 1, wn = wid & 1;
    int rowBase = blockIdx.x * 128 + wm * 64;
    int colBase = blockIdx.y * 128 + wn * 64;
    int l15 = lane & 15, l4 = lane >> 4;

    f32x4 acc[4][4] = {};
#pragma unroll
    for (int ks = 0; ks < K / 32; ++ks) {
        h8 af[4], bf[4];
#pragma unroll
        for (int mi = 0; mi < 4; ++mi)
            af[mi] = *(const h8*)(A + (size_t)(rowBase + mi * 16 + l15) * K + ks * 32 + l4 * 8);
#pragma unroll
        for (int ni = 0; ni < 4; ++ni)
            bf[ni] = *(const h8*)(Wp + ((size_t)(ks * 4 + l4) * NT + colBase + ni * 16 + l15) * 8);
#pragma unroll
        for (int mi = 0; mi < 4; ++mi)
#pragma unroll
            for (int ni = 0; ni < 4; ++ni)
                acc[mi][ni] = __builtin_amdgcn_mfma_f32_16x16x32_f16(af[mi], bf[ni], acc[mi][ni], 0, 0, 0);
    }

    int seg = colBase >> 8;
    int cbase = colBase & 255;
    if (o32 != nullptr && seg == 2) {
#pragma unroll
        for (int mi = 0; mi < 4; ++mi)
#pragma unroll
            for (int ni = 0; ni < 4; ++ni) {
                int c = cbase + ni * 16 + l15;
                float bv = bias[c];
#pragma unroll
                for (int q = 0; q < 4; ++q) {
                    int r = rowBase + mi * 16 + l4 * 4 + q;
                    o32[(size_t)r * 256 + c] = acc[mi][ni][q] + bv;
                }
            }
    } else {
        _Float16* o = (seg == 0) ? o16a : o16b;
#pragma unroll
        for (int mi = 0; mi < 4; ++mi)
#pragma unroll
            for (int ni = 0; ni < 4; ++ni) {
                int c = cbase + ni * 16 + l15;
#pragma unroll
                for (int q = 0; q < 4; ++q) {
                    int r = rowBase + mi * 16 + l4 * 4 + q;
                    o[(size_t)r * 256 + c] = (_Float16)acc[mi][ni][q];
                }
            }
    }
}

// ---------------------------------------------------------------------------
// GATv2 edge-softmax + aggregate, 16-lanes-per-edge, 2-edge-merged updates.
// R12 additions: (a) defer-max rescale-skip (exact math; rescale only when
// max grows by >8), (b) software-pipelined esrc index prefetch (2 VGPR),
// (c) fdot2 chain split in two. No min-waves clamp (R10: spills disaster).
// OMODE: 0 = fp32 out only, 1 = fp32 + fp16, 2 = fp16 only.
// ---------------------------------------------------------------------------
template<int H, int OMODE>
__global__ __launch_bounds__(256) void gat_agg_kernel(const _Float16* __restrict__ xl,
                                                      const _Float16* __restrict__ xr,
                                                      const float* __restrict__ att,
                                                      const float* __restrict__ bias,
                                                      const float* __restrict__ resid,
                                                      const int* __restrict__ offs,
                                                      const int* __restrict__ esrc,
                                                      float* __restrict__ out,
                                                      _Float16* __restrict__ out16) {
    int tid = threadIdx.x;
    int wid = tid >> 6;
    int lane = tid & 63;
    int node = blockIdx.x * 4 + wid;
    int g  = lane >> 4;      // edge slot 0..3
    int li = lane & 15;      // owns dims [16*li, 16*li+16)

    h2 xrv[8];
    {
        const h8* xp = (const h8*)(xr + ((size_t)node << 8) + (li << 4));
        h8 a0 = xp[0], a1 = xp[1];
#pragma unroll
        for (int i = 0; i < 4; ++i) { xrv[i][0] = a0[2 * i]; xrv[i][1] = a0[2 * i + 1]; }
#pragma unroll
        for (int i = 0; i < 4; ++i) { xrv[4 + i][0] = a1[2 * i]; xrv[4 + i][1] = a1[2 * i + 1]; }
    }
    h2 attv[8];
    {
        const float4* ap = (const float4*)(att + (li << 4));
#pragma unroll
        for (int i = 0; i < 4; ++i) {
            float4 a = ap[i];
            attv[2 * i][0] = (_Float16)a.x; attv[2 * i][1] = (_Float16)a.y;
            attv[2 * i + 1][0] = (_Float16)a.z; attv[2 * i + 1][1] = (_Float16)a.w;
        }
    }
    const h2 negc = { (_Float16)NEG, (_Float16)NEG };

    // prefetch epilogue operands early (independent of the loop)
    int dbase = (li << 4) + (g << 2);
    float4 bv = *(const float4*)(bias + dbase);
    float4 rv = *(const float4*)(resid + ((size_t)node << 8) + dbase);

    float m = -1e30f, s = 0.f;
    f32x2 acc2[8];
#pragma unroll
    for (int i = 0; i < 8; ++i) acc2[i] = (f32x2){0.f, 0.f};

    int e0 = offs[node];
    int total = offs[node + 1] - e0 + 1;      // +1 self-loop (virtual idx 0)

    auto gather = [&](int srcn, h2* hv) {
        const h8* xp = (const h8*)(xl + ((size_t)srcn << 8) + (li << 4));
        h8 a0 = xp[0], a1 = xp[1];
#pragma unroll
        for (int i = 0; i < 4; ++i) { hv[i][0] = a0[2 * i]; hv[i][1] = a0[2 * i + 1]; }
#pragma unroll
        for (int i = 0; i < 4; ++i) { hv[4 + i][0] = a1[2 * i]; hv[4 + i][1] = a1[2 * i + 1]; }
    };
    auto logit = [&](const h2* hv) -> float {
        float p0 = 0.f, p1 = 0.f;
#pragma unroll
        for (int i = 0; i < 4; ++i) {
            h2 sum = hv[i] + xrv[i];
            h2 lr = __builtin_elementwise_max(sum, sum * negc);
            p0 = __builtin_amdgcn_fdot2(lr, attv[i], p0, false);
            h2 sum2 = hv[4 + i] + xrv[4 + i];
            h2 lr2 = __builtin_elementwise_max(sum2, sum2 * negc);
            p1 = __builtin_amdgcn_fdot2(lr2, attv[4 + i], p1, false);
        }
        float part = p0 + p1;
        part += __shfl_xor(part, 1);
        part += __shfl_xor(part, 2);
        if constexpr (H == 1) {
            part += __shfl_xor(part, 4);
            part += __shfl_xor(part, 8);
        }
        return part;
    };

    int vi = g;
    // prefetched indices for the 2-edge pipeline (edges vi and vi+4)
    int sA = 0, sB = 0;
    if (vi + 4 < total) {
        sA = (vi == 0) ? node : esrc[e0 + vi - 1];
        sB = esrc[e0 + vi + 3];
    }
    for (; vi + 4 < total; vi += 8) {
        // prefetch next iteration's indices (clamped; harmless over-read)
        int nvi = vi + 8;
        int ia = e0 + nvi - 1; if (ia > E_EDGES - 1) ia = E_EDGES - 1;
        int ib = e0 + nvi + 3; if (ib > E_EDGES - 1) ib = E_EDGES - 1;
        int sA2 = esrc[ia];
        int sB2 = esrc[ib];

        h2 hA[8], hB[8];
        gather(sA, hA);
        gather(sB, hB);
        float lpA = logit(hA);
        float lpB = logit(hB);
        float mx = fmaxf(lpA, lpB);
        if (mx > m + 8.f) {
            // rescale path (rare after first iteration)
            float c  = __expf(m - mx);
            float pA = __expf(lpA - mx);
            float pB = __expf(lpB - mx);
            s = s * c + pA + pB;
#pragma unroll
            for (int i = 0; i < 8; ++i) {
                f32x2 t = acc2[i] * c;
                t[0] = fmaf(pA, (float)hA[i][0], t[0]);
                t[1] = fmaf(pA, (float)hA[i][1], t[1]);
                t[0] = fmaf(pB, (float)hB[i][0], t[0]);
                t[1] = fmaf(pB, (float)hB[i][1], t[1]);
                acc2[i] = t;
            }
            m = mx;
        } else {
            // defer-max: keep m; p bounded by e^8 (fp32 headroom fine)
            float pA = __expf(lpA - m);
            float pB = __expf(lpB - m);
            s += pA + pB;
#pragma unroll
            for (int i = 0; i < 8; ++i) {
                f32x2 t = acc2[i];
                t[0] = fmaf(pA, (float)hA[i][0], t[0]);
                t[1] = fmaf(pA, (float)hA[i][1], t[1]);
                t[0] = fmaf(pB, (float)hB[i][0], t[0]);
                t[1] = fmaf(pB, (float)hB[i][1], t[1]);
                acc2[i] = t;
            }
        }
        sA = sA2; sB = sB2;
    }
    // tail: single edges
    for (; vi < total; vi += 4) {
        int srcn = (vi == 0) ? node : esrc[e0 + vi - 1];
        h2 hA[8];
        gather(srcn, hA);
        float lp = logit(hA);
        if (lp > m + 8.f) {
            float c = __expf(m - lp);
            float p = 1.f;                    // exp(lp - lp)
            s = s * c + p;
#pragma unroll
            for (int i = 0; i < 8; ++i) {
                f32x2 t = acc2[i] * c;
                t[0] = fmaf(p, (float)hA[i][0], t[0]);
                t[1] = fmaf(p, (float)hA[i][1], t[1]);
                acc2[i] = t;
            }
            m = lp;
        } else {
            float p = __expf(lp - m);
            s += p;
#pragma unroll
            for (int i = 0; i < 8; ++i) {
                f32x2 t = acc2[i];
                t[0] = fmaf(p, (float)hA[i][0], t[0]);
                t[1] = fmaf(p, (float)hA[i][1], t[1]);
                acc2[i] = t;
            }
        }
    }

    // flash-merge the 4 edge-slot partials across lane groups (exact with
    // deferred m: partials are sums of exp(lp - m_slot), rescaled by
    // exp(m_slot - M) here)
#pragma unroll
    for (int mask = 16; mask <= 32; mask <<= 1) {
        float m2 = __shfl_xor(m, mask);
        float s2 = __shfl_xor(s, mask);
        float M = fmaxf(m, m2);
        float c1 = __expf(m - M);
        float c2 = __expf(m2 - M);
        s = s * c1 + s2 * c2;
#pragma unroll
        for (int i = 0; i < 8; ++i) {
            float ax = __shfl_xor(acc2[i][0], mask);
            float ay = __shfl_xor(acc2[i][1], mask);
            acc2[i][0] = acc2[i][0] * c1 + ax * c2;
            acc2[i][1] = acc2[i][1] * c1 + ay * c2;
        }
        m = M;
    }

    // epilogue: lane stores float4 #g of its 16 dims (compile-time select)
    float inv = 1.f / s;
    float a0, a1v, a2, a3;
    if (g == 0)      { a0 = acc2[0][0]; a1v = acc2[0][1]; a2 = acc2[1][0]; a3 = acc2[1][1]; }
    else if (g == 1) { a0 = acc2[2][0]; a1v = acc2[2][1]; a2 = acc2[3][0]; a3 = acc2[3][1]; }
    else if (g == 2) { a0 = acc2[4][0]; a1v = acc2[4][1]; a2 = acc2[5][0]; a3 = acc2[5][1]; }
    else             { a0 = acc2[6][0]; a1v = acc2[6][1]; a2 = acc2[7][0]; a3 = acc2[7][1]; }
    float o0 = fmaxf(a0 * inv + bv.x, 0.f) + rv.x;
    float o1 = fmaxf(a1v * inv + bv.y, 0.f) + rv.y;
    float o2 = fmaxf(a2 * inv + bv.z, 0.f) + rv.z;
    float o3 = fmaxf(a3 * inv + bv.w, 0.f) + rv.w;
    if constexpr (OMODE != 2) {
        float4 ov = make_float4(o0, o1, o2, o3);
        *(float4*)(out + ((size_t)node << 8) + dbase) = ov;
    }
    if constexpr (OMODE != 0) {
        h4 hv;
        hv[0] = (_Float16)o0; hv[1] = (_Float16)o1;
        hv[2] = (_Float16)o2; hv[3] = (_Float16)o3;
        *(h4*)(out16 + ((size_t)node << 8) + dbase) = hv;
    }
}

// ---------------------------------------------------------------------------
// Fused MLP head, 16-row waves (4 waves/block, 64 rows/block):
//   out[n] = relu(relu(o316[n]@Wm1+bm1)@Wm2+bm2) @ Wm3 + bm3
// ---------------------------------------------------------------------------
__global__ __launch_bounds__(256) void mlp_head_kernel(const _Float16* __restrict__ A,
                                                       const _Float16* __restrict__ Wm1p,
                                                       const float* __restrict__ bm1,
                                                       const _Float16* __restrict__ Wm2p,
                                                       const float* __restrict__ bm2,
                                                       const float* __restrict__ Wm3,
                                                       const float* __restrict__ bm3,
                                                       float* __restrict__ out) {
    __shared__ _Float16 t1s[4][16][72];
    int tid = threadIdx.x;
    int lane = tid & 63, wid = tid >> 6;
    int rowBase = blockIdx.x * 64 + wid * 16;
    int l15 = lane & 15, l4 = lane >> 4;

    f32x4 acc[4] = {};
#pragma unroll
    for (int ks = 0; ks < 8; ++ks) {
        h8 af = *(const h8*)(A + (size_t)(rowBase + l15) * 256 + ks * 32 + l4 * 8);
        h8 bf[4];
#pragma unroll
        for (int ni = 0; ni < 4; ++ni)
            bf[ni] = *(const h8*)(Wm1p + ((size_t)(ks * 4 + l4) * 64 + ni * 16 + l15) * 8);
#pragma unroll
        for (int ni = 0; ni < 4; ++ni)
            acc[ni] = __builtin_amdgcn_mfma_f32_16x16x32_f16(af, bf[ni], acc[ni], 0, 0, 0);
    }
#pragma unroll
    for (int ni = 0; ni < 4; ++ni) {
        int c = ni * 16 + l15;
        float bv = bm1[c];
#pragma unroll
        for (int q = 0; q < 4; ++q)
            t1s[wid][l4 * 4 + q][c] = (_Float16)fmaxf(acc[ni][q] + bv, 0.f);
    }

    f32x4 acc2[4] = {};
#pragma unroll
    for (int ks = 0; ks < 2; ++ks) {
        h8 af = *(const h8*)&t1s[wid][l15][ks * 32 + l4 * 8];
        h8 bf[4];
#pragma unroll
        for (int ni = 0; ni < 4; ++ni)
            bf[ni] = *(const h8*)(Wm2p + ((size_t)(ks * 4 + l4) * 64 + ni * 16 + l15) * 8);
#pragma unroll
        for (int ni = 0; ni < 4; ++ni)
            acc2[ni] = __builtin_amdgcn_mfma_f32_16x16x32_f16(af, bf[ni], acc2[ni], 0, 0, 0);
    }

    float b3 = bm3[0];
    float b2v[4], w3v[4];
#pragma unroll
    for (int ni = 0; ni < 4; ++ni) {
        b2v[ni] = bm2[ni * 16 + l15];
        w3v[ni] = Wm3[ni * 16 + l15];
    }
#pragma unroll
    for (int q = 0; q < 4; ++q) {
        float part = 0.f;
#pragma unroll
        for (int ni = 0; ni < 4; ++ni)
            part += fmaxf(acc2[ni][q] + b2v[ni], 0.f) * w3v[ni];
        part += __shfl_xor(part, 1);
        part += __shfl_xor(part, 2);
        part += __shfl_xor(part, 4);
        part += __shfl_xor(part, 8);
        if (l15 == 0)
            out[rowBase + l4 * 4 + q] = part + b3;
    }
}

// ---------------------------------------------------------------------------
extern "C" void kernel_launch(void* const* d_in, const int* in_sizes, int n_in,
                              void* d_out, int out_size, void* d_ws, size_t ws_size,
                              hipStream_t stream) {
    const float* x     = (const float*)d_in[0];
    const int*   ei    = (const int*)d_in[1];
    const float* Win   = (const float*)d_in[2];
    const float* b_in  = (const float*)d_in[3];
    const float* Wskip = (const float*)d_in[4];
    const float* bskip = (const float*)d_in[5];
    const float* Wl1   = (const float*)d_in[6];
    const float* Wr1   = (const float*)d_in[7];
    const float* att1  = (const float*)d_in[8];
    const float* b1    = (const float*)d_in[9];
    const float* Wl2   = (const float*)d_in[10];
    const float* Wr2   = (const float*)d_in[11];
    const float* att2  = (const float*)d_in[12];
    const float* b2    = (const float*)d_in[13];
    const float* Wl3   = (const float*)d_in[14];
    const float* Wr3   = (const float*)d_in[15];
    const float* att3  = (const float*)d_in[16];
    const float* b3    = (const float*)d_in[17];
    const float* Wm1   = (const float*)d_in[18];
    const float* bm1   = (const float*)d_in[19];
    const float* Wm2   = (const float*)d_in[20];
    const float* bm2   = (const float*)d_in[21];
    const float* Wm3   = (const float*)d_in[22];
    const float* bm3   = (const float*)d_in[23];

    // ---- workspace layout ----
    char* p = (char*)d_ws;
    auto alloc = [&](size_t bytes) { char* r = p; p += (bytes + 255) & ~(size_t)255; return r; };
    const size_t NN = N_NODES;
    float*    skip = (float*)alloc(NN * 256 * 4);   // also out2
    float*    out1 = (float*)alloc(NN * 256 * 4);
    _Float16* o116 = (_Float16*)alloc(NN * 256 * 2);
    _Float16* o216 = (_Float16*)alloc(NN * 256 * 2);
    _Float16* o316 = o116;                          // o116 dead by gat3
    _Float16* h16  = (_Float16*)alloc(NN * 64 * 2);
    _Float16* xl16 = (_Float16*)alloc(NN * 256 * 2);
    _Float16* xr16 = (_Float16*)alloc(NN * 256 * 2);
    _Float16* Wp1  = (_Float16*)alloc((size_t)64 * 768 * 2);
    _Float16* Wp2  = (_Float16*)alloc((size_t)256 * 512 * 2);
    _Float16* Wp3  = (_Float16*)alloc((size_t)256 * 512 * 2);
    _Float16* Winp = (_Float16*)alloc((size_t)128 * 64 * 2);
    _Float16* Wm1p = (_Float16*)alloc((size_t)256 * 64 * 2);
    _Float16* Wm2p = (_Float16*)alloc((size_t)64 * 64 * 2);
    int* cnt    = (int*)alloc(N_NODES * 4);
    int* offs   = (int*)alloc((N_NODES + 1) * 4);
    int* cursor = (int*)alloc(N_NODES * 4);
    int* esrc   = (int*)alloc(E_EDGES * 4);

    const int* src = ei;
    const int* dst = ei + E_EDGES;

    // ---- pack all weights + zero cnt (one launch) ----
    PackJobs jobs = {{
        { Wl1,   Wp1,  64,  256, 768, 0   },
        { Wr1,   Wp1,  64,  256, 768, 256 },
        { Wskip, Wp1,  64,  256, 768, 512 },
        { Wl2,   Wp2,  256, 256, 512, 0   },
        { Wr2,   Wp2,  256, 256, 512, 256 },
        { Wl3,   Wp3,  256, 256, 512, 0   },
        { Wr3,   Wp3,  256, 256, 512, 256 },
        { Win,   Winp, 128, 64,  64,  0   },
        { Wm1,   Wm1p, 256, 64,  64,  0   },
        { Wm2,   Wm2p, 64,  64,  64,  0   },
    }};
    pack_all_kernel<<<dim3(256, 11), 256, 0, stream>>>(jobs, cnt);

    // ---- CSR build ----
    hist_kernel<<<E_EDGES / 256, 256, 0, stream>>>(dst, cnt);
    csr_scan_kernel<<<1, 256, 0, stream>>>(cnt, offs, cursor);
    scatter_kernel<<<E_EDGES / 256, 256, 0, stream>>>(src, dst, cursor, esrc);

    // ---- input proj: h16 = fp16(relu(x @ Win + b_in)), cast fused ----
    mfma_n64_kernel<128, true, true, true><<<N_NODES / 64, 64, 0, stream>>>(x, Winp, b_in, h16);

    // ---- conv1: xl|xr|skip in one MFMA GEMM ----
    mfma_gemm_kernel<64><<<dim3(128, 6), 256, 0, stream>>>(h16, Wp1, 768, xl16, xr16, skip, bskip);
    gat_agg_kernel<4, 1><<<N_NODES / 4, 256, 0, stream>>>(xl16, xr16, att1, b1, skip, offs, esrc, out1, o116);

    // ---- conv2 ----
    mfma_gemm_kernel<256><<<dim3(128, 4), 256, 0, stream>>>(o116, Wp2, 512, xl16, xr16, nullptr, nullptr);
    gat_agg_kernel<1, 1><<<N_NODES / 4, 256, 0, stream>>>(xl16, xr16, att2, b2, out1, offs, esrc, skip /*out2*/, o216);

    // ---- conv3 (fp16-only output) ----
    mfma_gemm_kernel<256><<<dim3(128, 4), 256, 0, stream>>>(o216, Wp3, 512, xl16, xr16, nullptr, nullptr);
    gat_agg_kernel<1, 2><<<N_NODES / 4, 256, 0, stream>>>(xl16, xr16, att3, b3, skip /*out2*/, offs, esrc, nullptr, o316);

    // ---- fused MLP head ----
    mlp_head_kernel<<<N_NODES / 64, 256, 0, stream>>>(o316, Wm1p, bm1, Wm2p, bm2, Wm3, bm3, (float*)d_out);
}

// Round 14
// 194.602 us; speedup vs baseline: 1.4553x; 1.0037x over previous
//
#include <hip/hip_runtime.h>
#include <cstdint>
#include <cstddef>

#define N_NODES 16384
#define E_EDGES 262144
#define FIN     128
#define DIM     64
#define HID     256
#define NEG     0.2f

typedef _Float16 h8 __attribute__((ext_vector_type(8)));
typedef _Float16 h4 __attribute__((ext_vector_type(4)));
typedef _Float16 h2 __attribute__((ext_vector_type(2)));
typedef float    f32x4 __attribute__((ext_vector_type(4)));
typedef float    f32x2 __attribute__((ext_vector_type(2)));

// ---------------------------------------------------------------------------
// Device bodies (shared by plain and fused kernels)
// ---------------------------------------------------------------------------
__device__ __forceinline__ void csr_scan_body(const int* __restrict__ cnt,
                                              int* __restrict__ offs,
                                              int* __restrict__ cursor, int tid) {
    __shared__ int wsum[4];
    int lane = tid & 63, w = tid >> 6;
    int base = tid * 64;
    const int4* c4 = (const int4*)(cnt + base);
    int4 v[16];
    int s = 0;
#pragma unroll
    for (int i = 0; i < 16; ++i) {
        v[i] = c4[i];
        s += v[i].x + v[i].y + v[i].z + v[i].w;
    }
    int scan = s;
#pragma unroll
    for (int off = 1; off < 64; off <<= 1) {
        int t = __shfl_up(scan, off);
        if (lane >= off) scan += t;
    }
    if (lane == 63) wsum[w] = scan;
    __syncthreads();
    int wbase = 0;
#pragma unroll
    for (int i = 0; i < 4; ++i) if (i < w) wbase += wsum[i];
    int run = wbase + (scan - s);
#pragma unroll
    for (int i = 0; i < 16; ++i) {
        int4 o;
        o.x = run;
        o.y = o.x + v[i].x;
        o.z = o.y + v[i].y;
        o.w = o.z + v[i].z;
        *(int4*)(offs + base + 4 * i) = o;
        *(int4*)(cursor + base + 4 * i) = o;
        run = o.w + v[i].w;
    }
    if (tid == 255) offs[N_NODES] = run;
}

template<int K, bool RELU, bool O16, bool IN32>
__device__ __forceinline__ void mfma_n64_body(const void* __restrict__ Av,
                                              const _Float16* __restrict__ Wp,
                                              const float* __restrict__ bias,
                                              void* __restrict__ outv,
                                              int rowBase, int lane) {
    int l15 = lane & 15, l4 = lane >> 4;
    f32x4 acc[4][4] = {};
#pragma unroll
    for (int ks = 0; ks < K / 32; ++ks) {
        h8 af[4], bf[4];
#pragma unroll
        for (int mi = 0; mi < 4; ++mi) {
            if constexpr (IN32) {
                const float* ap = (const float*)Av + (size_t)(rowBase + mi * 16 + l15) * K + ks * 32 + l4 * 8;
                float4 a0 = *(const float4*)ap;
                float4 a1 = *(const float4*)(ap + 4);
                h8 v;
                v[0] = (_Float16)a0.x; v[1] = (_Float16)a0.y;
                v[2] = (_Float16)a0.z; v[3] = (_Float16)a0.w;
                v[4] = (_Float16)a1.x; v[5] = (_Float16)a1.y;
                v[6] = (_Float16)a1.z; v[7] = (_Float16)a1.w;
                af[mi] = v;
            } else {
                af[mi] = *(const h8*)((const _Float16*)Av + (size_t)(rowBase + mi * 16 + l15) * K + ks * 32 + l4 * 8);
            }
        }
#pragma unroll
        for (int ni = 0; ni < 4; ++ni)
            bf[ni] = *(const h8*)(Wp + ((size_t)(ks * 4 + l4) * 64 + ni * 16 + l15) * 8);
#pragma unroll
        for (int mi = 0; mi < 4; ++mi)
#pragma unroll
            for (int ni = 0; ni < 4; ++ni)
                acc[mi][ni] = __builtin_amdgcn_mfma_f32_16x16x32_f16(af[mi], bf[ni], acc[mi][ni], 0, 0, 0);
    }
#pragma unroll
    for (int mi = 0; mi < 4; ++mi)
#pragma unroll
        for (int ni = 0; ni < 4; ++ni) {
            int c = ni * 16 + l15;
            float bv = bias[c];
#pragma unroll
            for (int q = 0; q < 4; ++q) {
                int r = rowBase + mi * 16 + l4 * 4 + q;
                float v = acc[mi][ni][q] + bv;
                if (RELU) v = fmaxf(v, 0.f);
                if constexpr (O16) ((_Float16*)outv)[(size_t)r * 64 + c] = (_Float16)v;
                else               ((float*)outv)[(size_t)r * 64 + c] = v;
            }
        }
}

template<int K>
__device__ __forceinline__ void mfma_gemm_body(const _Float16* __restrict__ A,
                                               const _Float16* __restrict__ Wp,
                                               int NT,
                                               _Float16* __restrict__ o16a,
                                               _Float16* __restrict__ o16b,
                                               float* __restrict__ o32,
                                               const float* __restrict__ bias,
                                               int bx, int by, int tid) {
    int lane = tid & 63, wid = tid >> 6;
    int wm = wid >> 1, wn = wid & 1;
    int rowBase = bx * 128 + wm * 64;
    int colBase = by * 128 + wn * 64;
    int l15 = lane & 15, l4 = lane >> 4;

    f32x4 acc[4][4] = {};
#pragma unroll
    for (int ks = 0; ks < K / 32; ++ks) {
        h8 af[4], bf[4];
#pragma unroll
        for (int mi = 0; mi < 4; ++mi)
            af[mi] = *(const h8*)(A + (size_t)(rowBase + mi * 16 + l15) * K + ks * 32 + l4 * 8);
#pragma unroll
        for (int ni = 0; ni < 4; ++ni)
            bf[ni] = *(const h8*)(Wp + ((size_t)(ks * 4 + l4) * NT + colBase + ni * 16 + l15) * 8);
#pragma unroll
        for (int mi = 0; mi < 4; ++mi)
#pragma unroll
            for (int ni = 0; ni < 4; ++ni)
                acc[mi][ni] = __builtin_amdgcn_mfma_f32_16x16x32_f16(af[mi], bf[ni], acc[mi][ni], 0, 0, 0);
    }

    int seg = colBase >> 8;
    int cbase = colBase & 255;
    if (o32 != nullptr && seg == 2) {
#pragma unroll
        for (int mi = 0; mi < 4; ++mi)
#pragma unroll
            for (int ni = 0; ni < 4; ++ni) {
                int c = cbase + ni * 16 + l15;
                float bv = bias[c];
#pragma unroll
                for (int q = 0; q < 4; ++q) {
                    int r = rowBase + mi * 16 + l4 * 4 + q;
                    o32[(size_t)r * 256 + c] = acc[mi][ni][q] + bv;
                }
            }
    } else {
        _Float16* o = (seg == 0) ? o16a : o16b;
#pragma unroll
        for (int mi = 0; mi < 4; ++mi)
#pragma unroll
            for (int ni = 0; ni < 4; ++ni) {
                int c = cbase + ni * 16 + l15;
#pragma unroll
                for (int q = 0; q < 4; ++q) {
                    int r = rowBase + mi * 16 + l4 * 4 + q;
                    o[(size_t)r * 256 + c] = (_Float16)acc[mi][ni][q];
                }
            }
    }
}

// ---------------------------------------------------------------------------
// Multi-job weight pack + cnt-zero (job y==10).
// ---------------------------------------------------------------------------
struct PackJob { const float* W; _Float16* dst; int Ksrc, Nsrc, NT, colOff; };
struct PackJobs { PackJob j[10]; };

__global__ __launch_bounds__(256) void pack_all_kernel(PackJobs jobs, int* __restrict__ cnt) {
    int i = blockIdx.x * 256 + threadIdx.x;
    if (blockIdx.y == 10) {
        if (i < N_NODES) cnt[i] = 0;
        return;
    }
    PackJob jb = jobs.j[blockIdx.y];
    if (i < jb.Ksrc * jb.Nsrc) {
        int k = i / jb.Nsrc, n = i % jb.Nsrc;
        jb.dst[((size_t)(k >> 3) * jb.NT + jb.colOff + n) * 8 + (k & 7)] = (_Float16)jb.W[i];
    }
}

// ---------------------------------------------------------------------------
// Fused: degree histogram (blocks 0..1023) || input-proj MFMA (blocks 1024+).
// ---------------------------------------------------------------------------
__global__ __launch_bounds__(256) void hist_inproj_kernel(const int* __restrict__ dst,
                                                          int* __restrict__ cnt,
                                                          const float* __restrict__ x,
                                                          const _Float16* __restrict__ Winp,
                                                          const float* __restrict__ b_in,
                                                          _Float16* __restrict__ h16) {
    int bx = blockIdx.x;
    if (bx < E_EDGES / 256) {
        int i = bx * 256 + threadIdx.x;
        atomicAdd(&cnt[dst[i]], 1);
        return;
    }
    int tid = threadIdx.x;
    int wid = tid >> 6, lane = tid & 63;
    int rowBase = (bx - E_EDGES / 256) * 256 + wid * 64;
    mfma_n64_body<FIN, true, true, true>(x, Winp, b_in, h16, rowBase, lane);
}

// ---------------------------------------------------------------------------
// Fused: conv1 triple-GEMM (grid.y 0..5) || CSR scan (grid.y==6, x==0).
// ---------------------------------------------------------------------------
__global__ __launch_bounds__(256) void conv1_scan_kernel(const _Float16* __restrict__ A,
                                                         const _Float16* __restrict__ Wp,
                                                         _Float16* __restrict__ xl16,
                                                         _Float16* __restrict__ xr16,
                                                         float* __restrict__ skip,
                                                         const float* __restrict__ bskip,
                                                         const int* __restrict__ cnt,
                                                         int* __restrict__ offs,
                                                         int* __restrict__ cursor) {
    if (blockIdx.y == 6) {
        if (blockIdx.x == 0) csr_scan_body(cnt, offs, cursor, threadIdx.x);
        return;
    }
    mfma_gemm_body<64>(A, Wp, 768, xl16, xr16, skip, bskip, blockIdx.x, blockIdx.y, threadIdx.x);
}

__global__ __launch_bounds__(256) void scatter_kernel(const int* __restrict__ src,
                                                      const int* __restrict__ dst,
                                                      int* __restrict__ cursor,
                                                      int* __restrict__ esrc) {
    int i = blockIdx.x * 256 + threadIdx.x;
    if (i < E_EDGES) {
        int p = atomicAdd(&cursor[dst[i]], 1);
        esrc[p] = src[i];
    }
}

// ---------------------------------------------------------------------------
// Plain wide MFMA GEMM (conv2 / conv3).
// ---------------------------------------------------------------------------
template<int K>
__global__ __launch_bounds__(256) void mfma_gemm_kernel(const _Float16* __restrict__ A,
                                                        const _Float16* __restrict__ Wp,
                                                        int NT,
                                                        _Float16* __restrict__ o16a,
                                                        _Float16* __restrict__ o16b,
                                                        float* __restrict__ o32,
                                                        const float* __restrict__ bias) {
    mfma_gemm_body<K>(A, Wp, NT, o16a, o16b, o32, bias, blockIdx.x, blockIdx.y, threadIdx.x);
}

// ---------------------------------------------------------------------------
// GATv2 edge-softmax + aggregate, 16-lanes-per-edge, 2-edge-merged + defer-max.
// R14: nontemporal LOADS only (xr, resid) — R13's nontemporal STORES caused
// stale-L2 reads on graph replay (nt store writes around L2 without
// invalidating clean lines; skip-buffer reuse made staleness = wrong values).
// Stores are plain (coherent). No min-waves clamp (R10: spills).
// OMODE: 0 f32, 1 both, 2 f16.
// ---------------------------------------------------------------------------
template<int H, int OMODE>
__global__ __launch_bounds__(256) void gat_agg_kernel(const _Float16* __restrict__ xl,
                                                      const _Float16* __restrict__ xr,
                                                      const float* __restrict__ att,
                                                      const float* __restrict__ bias,
                                                      const float* __restrict__ resid,
                                                      const int* __restrict__ offs,
                                                      const int* __restrict__ esrc,
                                                      float* __restrict__ out,
                                                      _Float16* __restrict__ out16) {
    int tid = threadIdx.x;
    int wid = tid >> 6;
    int lane = tid & 63;
    int node = blockIdx.x * 4 + wid;
    int g  = lane >> 4;      // edge slot 0..3
    int li = lane & 15;      // owns dims [16*li, 16*li+16)

    h2 xrv[8];
    {
        const h8* xp = (const h8*)(xr + ((size_t)node << 8) + (li << 4));
        h8 a0 = __builtin_nontemporal_load(xp);
        h8 a1 = __builtin_nontemporal_load(xp + 1);
#pragma unroll
        for (int i = 0; i < 4; ++i) { xrv[i][0] = a0[2 * i]; xrv[i][1] = a0[2 * i + 1]; }
#pragma unroll
        for (int i = 0; i < 4; ++i) { xrv[4 + i][0] = a1[2 * i]; xrv[4 + i][1] = a1[2 * i + 1]; }
    }
    h2 attv[8];
    {
        const float4* ap = (const float4*)(att + (li << 4));
#pragma unroll
        for (int i = 0; i < 4; ++i) {
            float4 a = ap[i];
            attv[2 * i][0] = (_Float16)a.x; attv[2 * i][1] = (_Float16)a.y;
            attv[2 * i + 1][0] = (_Float16)a.z; attv[2 * i + 1][1] = (_Float16)a.w;
        }
    }
    const h2 negc = { (_Float16)NEG, (_Float16)NEG };

    // prefetch epilogue operands early (streaming -> nontemporal LOAD only)
    int dbase = (li << 4) + (g << 2);
    float4 bv = *(const float4*)(bias + dbase);
    f32x4 rv = __builtin_nontemporal_load((const f32x4*)(resid + ((size_t)node << 8) + dbase));

    float m = -1e30f, s = 0.f;
    f32x2 acc2[8];
#pragma unroll
    for (int i = 0; i < 8; ++i) acc2[i] = (f32x2){0.f, 0.f};

    int e0 = offs[node];
    int total = offs[node + 1] - e0 + 1;      // +1 self-loop (virtual idx 0)

    auto gather = [&](int srcn, h2* hv) {
        const h8* xp = (const h8*)(xl + ((size_t)srcn << 8) + (li << 4));
        h8 a0 = xp[0], a1 = xp[1];
#pragma unroll
        for (int i = 0; i < 4; ++i) { hv[i][0] = a0[2 * i]; hv[i][1] = a0[2 * i + 1]; }
#pragma unroll
        for (int i = 0; i < 4; ++i) { hv[4 + i][0] = a1[2 * i]; hv[4 + i][1] = a1[2 * i + 1]; }
    };
    auto logit = [&](const h2* hv) -> float {
        float p0 = 0.f, p1 = 0.f;
#pragma unroll
        for (int i = 0; i < 4; ++i) {
            h2 sum = hv[i] + xrv[i];
            h2 lr = __builtin_elementwise_max(sum, sum * negc);
            p0 = __builtin_amdgcn_fdot2(lr, attv[i], p0, false);
            h2 sum2 = hv[4 + i] + xrv[4 + i];
            h2 lr2 = __builtin_elementwise_max(sum2, sum2 * negc);
            p1 = __builtin_amdgcn_fdot2(lr2, attv[4 + i], p1, false);
        }
        float part = p0 + p1;
        part += __shfl_xor(part, 1);
        part += __shfl_xor(part, 2);
        if constexpr (H == 1) {
            part += __shfl_xor(part, 4);
            part += __shfl_xor(part, 8);
        }
        return part;
    };

    int vi = g;
    int sA = 0, sB = 0;
    if (vi + 4 < total) {
        sA = (vi == 0) ? node : esrc[e0 + vi - 1];
        sB = esrc[e0 + vi + 3];
    }
    for (; vi + 4 < total; vi += 8) {
        int nvi = vi + 8;
        int ia = e0 + nvi - 1; if (ia > E_EDGES - 1) ia = E_EDGES - 1;
        int ib = e0 + nvi + 3; if (ib > E_EDGES - 1) ib = E_EDGES - 1;
        int sA2 = esrc[ia];
        int sB2 = esrc[ib];

        h2 hA[8], hB[8];
        gather(sA, hA);
        gather(sB, hB);
        float lpA = logit(hA);
        float lpB = logit(hB);
        float mx = fmaxf(lpA, lpB);
        if (mx > m + 8.f) {
            float c  = __expf(m - mx);
            float pA = __expf(lpA - mx);
            float pB = __expf(lpB - mx);
            s = s * c + pA + pB;
#pragma unroll
            for (int i = 0; i < 8; ++i) {
                f32x2 t = acc2[i] * c;
                t[0] = fmaf(pA, (float)hA[i][0], t[0]);
                t[1] = fmaf(pA, (float)hA[i][1], t[1]);
                t[0] = fmaf(pB, (float)hB[i][0], t[0]);
                t[1] = fmaf(pB, (float)hB[i][1], t[1]);
                acc2[i] = t;
            }
            m = mx;
        } else {
            float pA = __expf(lpA - m);
            float pB = __expf(lpB - m);
            s += pA + pB;
#pragma unroll
            for (int i = 0; i < 8; ++i) {
                f32x2 t = acc2[i];
                t[0] = fmaf(pA, (float)hA[i][0], t[0]);
                t[1] = fmaf(pA, (float)hA[i][1], t[1]);
                t[0] = fmaf(pB, (float)hB[i][0], t[0]);
                t[1] = fmaf(pB, (float)hB[i][1], t[1]);
                acc2[i] = t;
            }
        }
        sA = sA2; sB = sB2;
    }
    for (; vi < total; vi += 4) {
        int srcn = (vi == 0) ? node : esrc[e0 + vi - 1];
        h2 hA[8];
        gather(srcn, hA);
        float lp = logit(hA);
        if (lp > m + 8.f) {
            float c = __expf(m - lp);
            s = s * c + 1.f;
#pragma unroll
            for (int i = 0; i < 8; ++i) {
                f32x2 t = acc2[i] * c;
                t[0] = t[0] + (float)hA[i][0];
                t[1] = t[1] + (float)hA[i][1];
                acc2[i] = t;
            }
            m = lp;
        } else {
            float p = __expf(lp - m);
            s += p;
#pragma unroll
            for (int i = 0; i < 8; ++i) {
                f32x2 t = acc2[i];
                t[0] = fmaf(p, (float)hA[i][0], t[0]);
                t[1] = fmaf(p, (float)hA[i][1], t[1]);
                acc2[i] = t;
            }
        }
    }

    // flash-merge the 4 edge-slot partials across lane groups
#pragma unroll
    for (int mask = 16; mask <= 32; mask <<= 1) {
        float m2 = __shfl_xor(m, mask);
        float s2 = __shfl_xor(s, mask);
        float M = fmaxf(m, m2);
        float c1 = __expf(m - M);
        float c2 = __expf(m2 - M);
        s = s * c1 + s2 * c2;
#pragma unroll
        for (int i = 0; i < 8; ++i) {
            float ax = __shfl_xor(acc2[i][0], mask);
            float ay = __shfl_xor(acc2[i][1], mask);
            acc2[i][0] = acc2[i][0] * c1 + ax * c2;
            acc2[i][1] = acc2[i][1] * c1 + ay * c2;
        }
        m = M;
    }

    // epilogue: lane stores float4 #g of its 16 dims (compile-time select)
    float inv = 1.f / s;
    float a0, a1v, a2, a3;
    if (g == 0)      { a0 = acc2[0][0]; a1v = acc2[0][1]; a2 = acc2[1][0]; a3 = acc2[1][1]; }
    else if (g == 1) { a0 = acc2[2][0]; a1v = acc2[2][1]; a2 = acc2[3][0]; a3 = acc2[3][1]; }
    else if (g == 2) { a0 = acc2[4][0]; a1v = acc2[4][1]; a2 = acc2[5][0]; a3 = acc2[5][1]; }
    else             { a0 = acc2[6][0]; a1v = acc2[6][1]; a2 = acc2[7][0]; a3 = acc2[7][1]; }
    float o0 = fmaxf(a0 * inv + bv.x, 0.f) + rv[0];
    float o1 = fmaxf(a1v * inv + bv.y, 0.f) + rv[1];
    float o2 = fmaxf(a2 * inv + bv.z, 0.f) + rv[2];
    float o3 = fmaxf(a3 * inv + bv.w, 0.f) + rv[3];
    if constexpr (OMODE != 2) {
        float4 ov = make_float4(o0, o1, o2, o3);
        *(float4*)(out + ((size_t)node << 8) + dbase) = ov;
    }
    if constexpr (OMODE != 0) {
        h4 hv;
        hv[0] = (_Float16)o0; hv[1] = (_Float16)o1;
        hv[2] = (_Float16)o2; hv[3] = (_Float16)o3;
        *(h4*)(out16 + ((size_t)node << 8) + dbase) = hv;
    }
}

// ---------------------------------------------------------------------------
// Fused MLP head, 16-row waves (4 waves/block, 64 rows/block).
// ---------------------------------------------------------------------------
__global__ __launch_bounds__(256) void mlp_head_kernel(const _Float16* __restrict__ A,
                                                       const _Float16* __restrict__ Wm1p,
                                                       const float* __restrict__ bm1,
                                                       const _Float16* __restrict__ Wm2p,
                                                       const float* __restrict__ bm2,
                                                       const float* __restrict__ Wm3,
                                                       const float* __restrict__ bm3,
                                                       float* __restrict__ out) {
    __shared__ _Float16 t1s[4][16][72];
    int tid = threadIdx.x;
    int lane = tid & 63, wid = tid >> 6;
    int rowBase = blockIdx.x * 64 + wid * 16;
    int l15 = lane & 15, l4 = lane >> 4;

    f32x4 acc[4] = {};
#pragma unroll
    for (int ks = 0; ks < 8; ++ks) {
        h8 af = __builtin_nontemporal_load((const h8*)(A + (size_t)(rowBase + l15) * 256 + ks * 32 + l4 * 8));
        h8 bf[4];
#pragma unroll
        for (int ni = 0; ni < 4; ++ni)
            bf[ni] = *(const h8*)(Wm1p + ((size_t)(ks * 4 + l4) * 64 + ni * 16 + l15) * 8);
#pragma unroll
        for (int ni = 0; ni < 4; ++ni)
            acc[ni] = __builtin_amdgcn_mfma_f32_16x16x32_f16(af, bf[ni], acc[ni], 0, 0, 0);
    }
#pragma unroll
    for (int ni = 0; ni < 4; ++ni) {
        int c = ni * 16 + l15;
        float bv = bm1[c];
#pragma unroll
        for (int q = 0; q < 4; ++q)
            t1s[wid][l4 * 4 + q][c] = (_Float16)fmaxf(acc[ni][q] + bv, 0.f);
    }

    f32x4 acc2[4] = {};
#pragma unroll
    for (int ks = 0; ks < 2; ++ks) {
        h8 af = *(const h8*)&t1s[wid][l15][ks * 32 + l4 * 8];
        h8 bf[4];
#pragma unroll
        for (int ni = 0; ni < 4; ++ni)
            bf[ni] = *(const h8*)(Wm2p + ((size_t)(ks * 4 + l4) * 64 + ni * 16 + l15) * 8);
#pragma unroll
        for (int ni = 0; ni < 4; ++ni)
            acc2[ni] = __builtin_amdgcn_mfma_f32_16x16x32_f16(af, bf[ni], acc2[ni], 0, 0, 0);
    }

    float b3 = bm3[0];
    float b2v[4], w3v[4];
#pragma unroll
    for (int ni = 0; ni < 4; ++ni) {
        b2v[ni] = bm2[ni * 16 + l15];
        w3v[ni] = Wm3[ni * 16 + l15];
    }
#pragma unroll
    for (int q = 0; q < 4; ++q) {
        float part = 0.f;
#pragma unroll
        for (int ni = 0; ni < 4; ++ni)
            part += fmaxf(acc2[ni][q] + b2v[ni], 0.f) * w3v[ni];
        part += __shfl_xor(part, 1);
        part += __shfl_xor(part, 2);
        part += __shfl_xor(part, 4);
        part += __shfl_xor(part, 8);
        if (l15 == 0)
            out[rowBase + l4 * 4 + q] = part + b3;
    }
}

// ---------------------------------------------------------------------------
extern "C" void kernel_launch(void* const* d_in, const int* in_sizes, int n_in,
                              void* d_out, int out_size, void* d_ws, size_t ws_size,
                              hipStream_t stream) {
    const float* x     = (const float*)d_in[0];
    const int*   ei    = (const int*)d_in[1];
    const float* Win   = (const float*)d_in[2];
    const float* b_in  = (const float*)d_in[3];
    const float* Wskip = (const float*)d_in[4];
    const float* bskip = (const float*)d_in[5];
    const float* Wl1   = (const float*)d_in[6];
    const float* Wr1   = (const float*)d_in[7];
    const float* att1  = (const float*)d_in[8];
    const float* b1    = (const float*)d_in[9];
    const float* Wl2   = (const float*)d_in[10];
    const float* Wr2   = (const float*)d_in[11];
    const float* att2  = (const float*)d_in[12];
    const float* b2    = (const float*)d_in[13];
    const float* Wl3   = (const float*)d_in[14];
    const float* Wr3   = (const float*)d_in[15];
    const float* att3  = (const float*)d_in[16];
    const float* b3    = (const float*)d_in[17];
    const float* Wm1   = (const float*)d_in[18];
    const float* bm1   = (const float*)d_in[19];
    const float* Wm2   = (const float*)d_in[20];
    const float* bm2   = (const float*)d_in[21];
    const float* Wm3   = (const float*)d_in[22];
    const float* bm3   = (const float*)d_in[23];

    // ---- workspace layout ----
    char* p = (char*)d_ws;
    auto alloc = [&](size_t bytes) { char* r = p; p += (bytes + 255) & ~(size_t)255; return r; };
    const size_t NN = N_NODES;
    float*    skip = (float*)alloc(NN * 256 * 4);   // also out2
    float*    out1 = (float*)alloc(NN * 256 * 4);
    _Float16* o116 = (_Float16*)alloc(NN * 256 * 2);
    _Float16* o216 = (_Float16*)alloc(NN * 256 * 2);
    _Float16* o316 = o116;                          // o116 dead by gat3
    _Float16* h16  = (_Float16*)alloc(NN * 64 * 2);
    _Float16* xl16 = (_Float16*)alloc(NN * 256 * 2);
    _Float16* xr16 = (_Float16*)alloc(NN * 256 * 2);
    _Float16* Wp1  = (_Float16*)alloc((size_t)64 * 768 * 2);
    _Float16* Wp2  = (_Float16*)alloc((size_t)256 * 512 * 2);
    _Float16* Wp3  = (_Float16*)alloc((size_t)256 * 512 * 2);
    _Float16* Winp = (_Float16*)alloc((size_t)128 * 64 * 2);
    _Float16* Wm1p = (_Float16*)alloc((size_t)256 * 64 * 2);
    _Float16* Wm2p = (_Float16*)alloc((size_t)64 * 64 * 2);
    int* cnt    = (int*)alloc(N_NODES * 4);
    int* offs   = (int*)alloc((N_NODES + 1) * 4);
    int* cursor = (int*)alloc(N_NODES * 4);
    int* esrc   = (int*)alloc(E_EDGES * 4);

    const int* src = ei;
    const int* dst = ei + E_EDGES;

    // ---- pack all weights + zero cnt (one launch) ----
    PackJobs jobs = {{
        { Wl1,   Wp1,  64,  256, 768, 0   },
        { Wr1,   Wp1,  64,  256, 768, 256 },
        { Wskip, Wp1,  64,  256, 768, 512 },
        { Wl2,   Wp2,  256, 256, 512, 0   },
        { Wr2,   Wp2,  256, 256, 512, 256 },
        { Wl3,   Wp3,  256, 256, 512, 0   },
        { Wr3,   Wp3,  256, 256, 512, 256 },
        { Win,   Winp, 128, 64,  64,  0   },
        { Wm1,   Wm1p, 256, 64,  64,  0   },
        { Wm2,   Wm2p, 64,  64,  64,  0   },
    }};
    pack_all_kernel<<<dim3(256, 11), 256, 0, stream>>>(jobs, cnt);

    // ---- hist || input-proj (both depend only on pack_all) ----
    hist_inproj_kernel<<<E_EDGES / 256 + N_NODES / 256, 256, 0, stream>>>(
        dst, cnt, x, Winp, b_in, h16);

    // ---- conv1 triple-GEMM || CSR scan ----
    conv1_scan_kernel<<<dim3(128, 7), 256, 0, stream>>>(
        h16, Wp1, xl16, xr16, skip, bskip, cnt, offs, cursor);

    // ---- scatter (needs scan) ----
    scatter_kernel<<<E_EDGES / 256, 256, 0, stream>>>(src, dst, cursor, esrc);

    // ---- conv1 aggregate ----
    gat_agg_kernel<4, 1><<<N_NODES / 4, 256, 0, stream>>>(xl16, xr16, att1, b1, skip, offs, esrc, out1, o116);

    // ---- conv2 ----
    mfma_gemm_kernel<256><<<dim3(128, 4), 256, 0, stream>>>(o116, Wp2, 512, xl16, xr16, nullptr, nullptr);
    gat_agg_kernel<1, 1><<<N_NODES / 4, 256, 0, stream>>>(xl16, xr16, att2, b2, out1, offs, esrc, skip /*out2*/, o216);

    // ---- conv3 (fp16-only output) ----
    mfma_gemm_kernel<256><<<dim3(128, 4), 256, 0, stream>>>(o216, Wp3, 512, xl16, xr16, nullptr, nullptr);
    gat_agg_kernel<1, 2><<<N_NODES / 4, 256, 0, stream>>>(xl16, xr16, att3, b3, skip /*out2*/, offs, esrc, nullptr, o316);

    // ---- fused MLP head ----
    mlp_head_kernel<<<N_NODES / 64, 256, 0, stream>>>(o316, Wm1p, bm1, Wm2p, bm2, Wm3, bm3, (float*)d_out);
}